// Round 5
// baseline (300.688 us; speedup 1.0000x reference)
//
#include <hip/hip_runtime.h>
#include <hip/hip_bf16.h>

typedef _Float16 f16;
typedef f16 f16x2 __attribute__((ext_vector_type(2)));
typedef f16 f16x4 __attribute__((ext_vector_type(4)));
typedef f16 f16x8 __attribute__((ext_vector_type(8)));
typedef float f32x2 __attribute__((ext_vector_type(2)));
typedef float f32x4 __attribute__((ext_vector_type(4)));

#define MFMA16(a, b, c) __builtin_amdgcn_mfma_f32_16x16x32_f16(a, b, c, 0, 0, 0)

__device__ __forceinline__ void glds16(const void* g, void* l) {
    __builtin_amdgcn_global_load_lds(
        (const __attribute__((address_space(1))) unsigned int*)g,
        (__attribute__((address_space(3))) unsigned int*)l, 16, 0, 0);
}

// packed f32 FMA: d = a*b + c per 32-bit half (2x f32 VALU rate)
__device__ __forceinline__ f32x2 pk_fma(f32x2 a, f32x2 b, f32x2 c) {
    f32x2 d;
    asm("v_pk_fma_f32 %0, %1, %2, %3" : "=v"(d) : "v"(a), "v"(b), "v"(c));
    return d;
}

// ---------------- f32 -> f16 convert ----------------
__global__ __launch_bounds__(256) void cvt_kernel(const float* __restrict__ s,
                                                  f16* __restrict__ d, int n) {
    int i = (blockIdx.x * 256 + threadIdx.x) * 8;
    if (i >= n) return;
    float4 a = *(const float4*)(s + i);
    float4 b = *(const float4*)(s + i + 4);
    f16x8 h;
    h[0] = (f16)a.x; h[1] = (f16)a.y; h[2] = (f16)a.z; h[3] = (f16)a.w;
    h[4] = (f16)b.x; h[5] = (f16)b.y; h[6] = (f16)b.z; h[7] = (f16)b.w;
    *(f16x8*)(d + i) = h;
}

// ---------------- GEMM: C[M,N] = A[M,K] @ B[N,K]^T + bias ----------------
// 128x128 tile, BK=32, 4 waves (2x2). XCD-swizzled. T3-minimum pipeline:
// double-buffered LDS, stage tile k+1 issued BEFORE computing tile k,
// single barrier per K-iter (vmcnt(0) drain overlaps compute).
// f32-A path: A prefetched to regs (T14), cvt+ds_write after MFMA.
template <bool A_F32, bool OUT_F16>
__global__ __launch_bounds__(256) void gemm_bt_kernel(
    const void* __restrict__ A_, const f16* __restrict__ Bw,
    const float* __restrict__ bias, void* __restrict__ C_, int M, int N, int K) {
    __shared__ f16 As[2][128 * 32];
    __shared__ f16 Bs[2][128 * 32];
    const int tid = threadIdx.x;
    const int lane = tid & 63;
    const int w = tid >> 6;
    const int nblk = N >> 7;
    const int cpx = (int)gridDim.x >> 3;
    const int logical = ((int)blockIdx.x & 7) * cpx + ((int)blockIdx.x >> 3);
    const int mb = logical / nblk, nb = logical % nblk;
    const int wm = w >> 1, wn = w & 1;
    const int q = lane >> 4, cl = lane & 15;

    const f16* Bbase = Bw + (size_t)nb * 128 * K;
    const float* A32 = (const float*)A_;
    const f16* A16 = (const f16*)A_;
    const int KT = K >> 5;

    f32x4 acc[4][4] = {};

    // ---- prologue: stage tile 0 into buffer 0 ----
    {
#pragma unroll
        for (int it = 0; it < 2; ++it) {
            int c = it * 256 + w * 64 + lane;
            glds16(Bbase + (size_t)(c >> 2) * K + (c & 3) * 8,
                   &Bs[0][(it * 256 + w * 64) * 8]);
        }
        if (A_F32) {
#pragma unroll
            for (int it = 0; it < 2; ++it) {
                int c = tid + it * 256;
                const float* sp = A32 + (size_t)(mb * 128 + (c >> 2)) * K + (c & 3) * 8;
                float4 a = *(const float4*)sp;
                float4 b = *(const float4*)(sp + 4);
                f16x8 h;
                h[0] = (f16)a.x; h[1] = (f16)a.y; h[2] = (f16)a.z; h[3] = (f16)a.w;
                h[4] = (f16)b.x; h[5] = (f16)b.y; h[6] = (f16)b.z; h[7] = (f16)b.w;
                *(f16x8*)&As[0][c * 8] = h;
            }
        } else {
#pragma unroll
            for (int it = 0; it < 2; ++it) {
                int c = it * 256 + w * 64 + lane;
                glds16(A16 + (size_t)(mb * 128 + (c >> 2)) * K + (c & 3) * 8,
                       &As[0][(it * 256 + w * 64) * 8]);
            }
        }
    }
    __syncthreads();

#pragma unroll 1
    for (int kt = 0; kt < KT; ++kt) {
        const int cur = kt & 1, nxt = cur ^ 1;
        const int k1 = (kt + 1) << 5;
        float4 pa[2], pb[2];
        // ---- issue tile kt+1 staging (overlaps compute below) ----
        if (kt + 1 < KT) {
#pragma unroll
            for (int it = 0; it < 2; ++it) {
                int c = it * 256 + w * 64 + lane;
                glds16(Bbase + (size_t)(c >> 2) * K + k1 + (c & 3) * 8,
                       &Bs[nxt][(it * 256 + w * 64) * 8]);
            }
            if (A_F32) {
#pragma unroll
                for (int it = 0; it < 2; ++it) {
                    int c = tid + it * 256;
                    const float* sp =
                        A32 + (size_t)(mb * 128 + (c >> 2)) * K + k1 + (c & 3) * 8;
                    pa[it] = *(const float4*)sp;
                    pb[it] = *(const float4*)(sp + 4);
                }
            } else {
#pragma unroll
                for (int it = 0; it < 2; ++it) {
                    int c = it * 256 + w * 64 + lane;
                    glds16(A16 + (size_t)(mb * 128 + (c >> 2)) * K + k1 + (c & 3) * 8,
                           &As[nxt][(it * 256 + w * 64) * 8]);
                }
            }
        }
        // ---- compute tile kt from buffer cur ----
        f16x8 af[4], bf[4];
#pragma unroll
        for (int mt = 0; mt < 4; ++mt)
            af[mt] = *(const f16x8*)&As[cur][(wm * 64 + mt * 16 + cl) * 32 + q * 8];
#pragma unroll
        for (int nt = 0; nt < 4; ++nt)
            bf[nt] = *(const f16x8*)&Bs[cur][(wn * 64 + nt * 16 + cl) * 32 + q * 8];
#pragma unroll
        for (int mt = 0; mt < 4; ++mt)
#pragma unroll
            for (int nt = 0; nt < 4; ++nt)
                acc[mt][nt] = MFMA16(af[mt], bf[nt], acc[mt][nt]);
        // ---- f32 path: convert prefetched A regs, write to nxt buffer ----
        // (safe without extra barrier: all waves' reads of As[nxt] happened
        //  in iter kt-1 and completed before the end-of-(kt-1) barrier)
        if (A_F32 && kt + 1 < KT) {
#pragma unroll
            for (int it = 0; it < 2; ++it) {
                int c = tid + it * 256;
                f16x8 h;
                h[0] = (f16)pa[it].x; h[1] = (f16)pa[it].y;
                h[2] = (f16)pa[it].z; h[3] = (f16)pa[it].w;
                h[4] = (f16)pb[it].x; h[5] = (f16)pb[it].y;
                h[6] = (f16)pb[it].z; h[7] = (f16)pb[it].w;
                *(f16x8*)&As[nxt][c * 8] = h;
            }
        }
        __syncthreads();  // drains vmcnt(0)+lgkm: tile kt+1 ready for next iter
    }

    float bv[4];
#pragma unroll
    for (int nt = 0; nt < 4; ++nt) bv[nt] = bias[nb * 128 + wn * 64 + nt * 16 + cl];
#pragma unroll
    for (int mt = 0; mt < 4; ++mt) {
#pragma unroll
        for (int nt = 0; nt < 4; ++nt) {
            size_t gr = (size_t)(mb * 128 + wm * 64 + mt * 16 + q * 4);
            int gc = nb * 128 + wn * 64 + nt * 16 + cl;
#pragma unroll
            for (int r = 0; r < 4; ++r) {
                float v = acc[mt][nt][r] + bv[nt];
                if (OUT_F16)
                    ((f16*)C_)[(gr + r) * N + gc] = (f16)v;
                else
                    ((float*)C_)[(gr + r) * N + gc] = v;
            }
        }
    }
}

// ---------------- segment-average partials ----------------
__global__ __launch_bounds__(256) void avg_kernel(const f16* __restrict__ X1h,
                                                  float* __restrict__ partial) {
    const int bn = blockIdx.x >> 2, rc = blockIdx.x & 3;
    const int tid = threadIdx.x;
    const f16* base = X1h + (size_t)bn * 262144 + (size_t)rc * 65536 + tid * 4;
    float s0 = 0.f, s1 = 0.f, s2 = 0.f, s3 = 0.f;
    for (int l = 0; l < 64; ++l) {
        f16x4 v = *(const f16x4*)(base + (size_t)l * 1024);
        s0 += (float)v[0]; s1 += (float)v[1]; s2 += (float)v[2]; s3 += (float)v[3];
    }
    const float sc = 1.f / 256.f;
    float4 o = make_float4(s0 * sc, s1 * sc, s2 * sc, s3 * sc);
    *(float4*)(partial + (size_t)(bn * 4 + rc) * 1024 + tid * 4) = o;
}

// ---------------- router ----------------
__global__ __launch_bounds__(64) void router_kernel(const float* __restrict__ partial,
                                                    const float* __restrict__ emb,
                                                    float* __restrict__ ew) {
    const int t = blockIdx.x;
    const int bn = t >> 3, h = t & 7;
    const int lane = threadIdx.x;
    float acc = 0.f;
    const float* p = partial + (size_t)bn * 4096 + h * 128;
    if (lane < 16) {
        for (int d = 0; d < 128; ++d) {
            float a = p[d] + p[d + 1024] + p[d + 2048] + p[d + 3072];
            acc = fmaf(a, emb[d * 16 + lane], acc);
        }
    }
    float m = acc;
#pragma unroll
    for (int o = 8; o; o >>= 1) m = fmaxf(m, __shfl_xor(m, o));
    float pr = __expf(acc - m);
    float s = pr;
#pragma unroll
    for (int o = 8; o; o >>= 1) s += __shfl_xor(s, o);
    if (lane < 16) ew[t * 16 + lane] = pr / s;
}

// ---------------- expert mixture (pk_fma version) ----------------
__global__ __launch_bounds__(256) void mix_kernel(const float* __restrict__ ew,
                                                  const float* __restrict__ FL,
                                                  const float* __restrict__ SL,
                                                  f16* __restrict__ m1h,
                                                  f16* __restrict__ m2h) {
    __shared__ f32x2 ews2[4096];  // [tt][e] duplicated {w,w}, 32KB
    const int bid = blockIdx.x;
    const int which = bid >> 8, th = (bid >> 7) & 1, chunk = bid & 127;
    const float* src = which ? SL : FL;
    f16* dst = which ? m2h : m1h;
    const int tid = threadIdx.x;
    const int e0 = chunk * 512 + tid * 2;
    f32x2 fl[16];
#pragma unroll
    for (int e = 0; e < 16; ++e)
        fl[e] = *(const f32x2*)(src + (size_t)e * 65536 + e0);
    for (int i = tid; i < 4096; i += 256) {
        float wv = ew[th * 4096 + i];
        f32x2 p; p.x = wv; p.y = wv;
        ews2[i] = p;
    }
    __syncthreads();
#pragma unroll 1
    for (int tt = 0; tt < 256; ++tt) {
        f32x2 a; a.x = 0.f; a.y = 0.f;
#pragma unroll
        for (int e = 0; e < 16; ++e)
            a = pk_fma(ews2[tt * 16 + e], fl[e], a);
        f16x2 h;
        h[0] = (f16)a.x; h[1] = (f16)a.y;
        *(f16x2*)(dst + (size_t)(th * 256 + tt) * 65536 + e0) = h;
    }
}

// ---------------- MLP: LDS-streamed weights ----------------
__device__ __forceinline__ void stage_w128(const f16* __restrict__ src, f16* lds,
                                           int w, int lane, int rowstride) {
#pragma unroll
    for (int it = 0; it < 8; ++it) {
        int cbase = it * 256 + w * 64;
        int c = cbase + lane;
        int row = c >> 4, pc = c & 15;
        int lc = pc ^ (row & 7);
        glds16(src + (size_t)row * rowstride + lc * 8, lds + cbase * 8);
    }
}

__global__ __launch_bounds__(256) void mlp_kernel(const f16* __restrict__ Xg,
                                                  const f16* __restrict__ m1h,
                                                  const f16* __restrict__ m2h,
                                                  f16* __restrict__ Yg) {
    __shared__ f16 Hs[128 * 128];
    __shared__ f16 Ws[128 * 128];
    // XCD swizzle over 1024 blocks (= 512 tiles x 2 halves): lh pair colocates
    const int cpx = (int)gridDim.x >> 3;
    const int logical = ((int)blockIdx.x & 7) * cpx + ((int)blockIdx.x >> 3);
    const int t = logical >> 1, lh = logical & 1;
    const int n = (t >> 3) & 15;
    const int tm = (n > 0) ? (t - 8) : t;
    const int tid = threadIdx.x;
    const int lane = tid & 63, w = tid >> 6;
    const int q = lane >> 4, cl = lane & 15;
    const int l0 = w * 32;

    const f16* Xsrc = Xg + (size_t)t * 32768 + lh * 16384;
    const f16* m1b = m1h + (size_t)tm * 65536;
    const f16* m2b = m2h + (size_t)tm * 65536;

    f16x8 xf[2][4];
#pragma unroll
    for (int lt = 0; lt < 2; ++lt) {
        int l = l0 + lt * 16 + cl;
#pragma unroll
        for (int ks = 0; ks < 4; ++ks)
            xf[lt][ks] = *(const f16x8*)(Xsrc + (size_t)l * 128 + ks * 32 + q * 8);
    }
    stage_w128(m1b, Ws, w, lane, 128);
    __syncthreads();

    f32x4 acc2[2][8] = {};
#pragma unroll 1
    for (int ic = 0; ic < 4; ++ic) {
        // ---- stage1: h^T over i-chunk, Ws = m1[ic] ----
#pragma unroll
        for (int it = 0; it < 8; ++it) {
            f16x8 af[4];
#pragma unroll
            for (int ks = 0; ks < 4; ++ks) {
                int r = it * 16 + cl;
                int ch = (ks * 4 + q) ^ (r & 7);
                af[ks] = *(const f16x8*)&Ws[r * 128 + ch * 8];
            }
            f32x4 a1[2] = {};
#pragma unroll
            for (int ks = 0; ks < 4; ++ks)
#pragma unroll
                for (int lt = 0; lt < 2; ++lt)
                    a1[lt] = MFMA16(af[ks], xf[lt][ks], a1[lt]);
            int ibase = it * 16 + q * 4;
            int ch = ibase >> 3;
            int sub = (q & 1) * 8;
#pragma unroll
            for (int lt = 0; lt < 2; ++lt) {
                int l = l0 + lt * 16 + cl;
                f16x4 hv;
                hv[0] = (f16)fmaxf(a1[lt][0], 0.f);
                hv[1] = (f16)fmaxf(a1[lt][1], 0.f);
                hv[2] = (f16)fmaxf(a1[lt][2], 0.f);
                hv[3] = (f16)fmaxf(a1[lt][3], 0.f);
                *(f16x4*)((char*)Hs + (size_t)l * 256 + ((ch ^ (l & 7)) << 4) + sub) = hv;
            }
        }
        __syncthreads();
        stage_w128(m2b + ic * 128, Ws, w, lane, 512);
        __syncthreads();

        // ---- stage2: acc2 += h @ m2[ic]^T ----
        f16x8 hf[2][4];
#pragma unroll
        for (int lt = 0; lt < 2; ++lt) {
            int l = l0 + lt * 16 + cl;
#pragma unroll
            for (int ks = 0; ks < 4; ++ks) {
                int ch = (ks * 4 + q) ^ (l & 7);
                hf[lt][ks] = *(const f16x8*)&Hs[l * 128 + ch * 8];
            }
        }
#pragma unroll
        for (int nt = 0; nt < 8; ++nt) {
            f16x8 bf[4];
#pragma unroll
            for (int ks = 0; ks < 4; ++ks) {
                int r = nt * 16 + cl;
                int ch = (ks * 4 + q) ^ (r & 7);
                bf[ks] = *(const f16x8*)&Ws[r * 128 + ch * 8];
            }
#pragma unroll
            for (int lt = 0; lt < 2; ++lt)
#pragma unroll
                for (int ks = 0; ks < 4; ++ks)
                    acc2[lt][nt] = MFMA16(hf[lt][ks], bf[ks], acc2[lt][nt]);
        }
        __syncthreads();
        if (ic < 3) {
            stage_w128(m1b + (size_t)(ic + 1) * 16384, Ws, w, lane, 128);
            __syncthreads();
        }
    }
    f16* Yb = Yg + (size_t)t * 32768 + lh * 16384;
#pragma unroll
    for (int lt = 0; lt < 2; ++lt) {
#pragma unroll
        for (int nt = 0; nt < 8; ++nt) {
            int lr = l0 + lt * 16 + q * 4;
            int d = nt * 16 + cl;
#pragma unroll
            for (int r = 0; r < 4; ++r)
                Yb[(size_t)(lr + r) * 128 + d] = (f16)acc2[lt][nt][r];
        }
    }
}

extern "C" void kernel_launch(void* const* d_in, const int* in_sizes, int n_in,
                              void* d_out, int out_size, void* d_ws, size_t ws_size,
                              hipStream_t stream) {
    const float* x    = (const float*)d_in[0];
    const float* W_mh = (const float*)d_in[1];
    const float* b_mh = (const float*)d_in[2];
    const float* W_mg = (const float*)d_in[3];
    const float* b_mg = (const float*)d_in[4];
    const float* emb  = (const float*)d_in[5];
    const float* FL   = (const float*)d_in[6];
    const float* SL   = (const float*)d_in[7];

    char* ws = (char*)d_ws;
    f16*   X1h  = (f16*)(ws + 0);
    f16*   m1h  = (f16*)(ws + 33554432);
    f16*   m2h  = (f16*)(ws + 100663296);
    f16*   Wmhh = (f16*)(ws + 167772160);
    f16*   Wmgh = (f16*)(ws + 169869312);
    float* part = (float*)(ws + 171966464);
    float* ew   = (float*)(ws + 173015040);

    cvt_kernel<<<512, 256, 0, stream>>>(W_mh, Wmhh, 1048576);
    cvt_kernel<<<512, 256, 0, stream>>>(W_mg, Wmgh, 1048576);
    gemm_bt_kernel<true, true><<<1024, 256, 0, stream>>>(x, Wmhh, b_mh, X1h,
                                                         16384, 1024, 1024);
    avg_kernel<<<256, 256, 0, stream>>>(X1h, part);
    router_kernel<<<512, 64, 0, stream>>>(part, emb, ew);
    mix_kernel<<<512, 256, 0, stream>>>(ew, FL, SL, m1h, m2h);
    mlp_kernel<<<1024, 256, 0, stream>>>(X1h, m1h, m2h, X1h);
    gemm_bt_kernel<false, false><<<1024, 256, 0, stream>>>(X1h, Wmgh, b_mg, d_out,
                                                           16384, 1024, 1024);
}

// Round 6
// 269.100 us; speedup vs baseline: 1.1174x; 1.1174x over previous
//
#include <hip/hip_runtime.h>
#include <hip/hip_bf16.h>

typedef _Float16 f16;
typedef f16 f16x2 __attribute__((ext_vector_type(2)));
typedef f16 f16x4 __attribute__((ext_vector_type(4)));
typedef f16 f16x8 __attribute__((ext_vector_type(8)));
typedef float f32x2 __attribute__((ext_vector_type(2)));
typedef float f32x4 __attribute__((ext_vector_type(4)));

#define MFMA16(a, b, c) __builtin_amdgcn_mfma_f32_16x16x32_f16(a, b, c, 0, 0, 0)

__device__ __forceinline__ void glds16(const void* g, void* l) {
    __builtin_amdgcn_global_load_lds(
        (const __attribute__((address_space(1))) unsigned int*)g,
        (__attribute__((address_space(3))) unsigned int*)l, 16, 0, 0);
}

// packed f32 FMA: d = a*b + c per 32-bit half (2x f32 VALU rate)
__device__ __forceinline__ f32x2 pk_fma(f32x2 a, f32x2 b, f32x2 c) {
    f32x2 d;
    asm("v_pk_fma_f32 %0, %1, %2, %3" : "=v"(d) : "v"(a), "v"(b), "v"(c));
    return d;
}

// ---------------- f32 -> f16 convert ----------------
__global__ __launch_bounds__(256) void cvt_kernel(const float* __restrict__ s,
                                                  f16* __restrict__ d, int n) {
    int i = (blockIdx.x * 256 + threadIdx.x) * 8;
    if (i >= n) return;
    float4 a = *(const float4*)(s + i);
    float4 b = *(const float4*)(s + i + 4);
    f16x8 h;
    h[0] = (f16)a.x; h[1] = (f16)a.y; h[2] = (f16)a.z; h[3] = (f16)a.w;
    h[4] = (f16)b.x; h[5] = (f16)b.y; h[6] = (f16)b.z; h[7] = (f16)b.w;
    *(f16x8*)(d + i) = h;
}

// ---------------- GEMM: C[M,N] = A[M,K] @ B[N,K]^T + bias ----------------
// R4-proven structure: 128x128 tile, BK=32, 4 waves (2x2), single-buffer LDS,
// 2 barriers/iter, glds16 staging both operands, XCD-swizzled blockIdx.
template <bool OUT_F16>
__global__ __launch_bounds__(256) void gemm_bt_kernel(
    const f16* __restrict__ A16, const f16* __restrict__ Bw,
    const float* __restrict__ bias, void* __restrict__ C_, int M, int N, int K) {
    __shared__ f16 As[128 * 32];
    __shared__ f16 Bs[128 * 32];
    const int tid = threadIdx.x;
    const int lane = tid & 63;
    const int w = tid >> 6;
    const int nblk = N >> 7;
    const int cpx = (int)gridDim.x >> 3;
    const int logical = ((int)blockIdx.x & 7) * cpx + ((int)blockIdx.x >> 3);
    const int mb = logical / nblk, nb = logical % nblk;
    const int wm = w >> 1, wn = w & 1;
    const int q = lane >> 4, cl = lane & 15;

    const f16* Bbase = Bw + (size_t)nb * 128 * K;

    f32x4 acc[4][4] = {};

#pragma unroll 1
    for (int kt = 0; kt < (K >> 5); ++kt) {
        const int k0 = kt << 5;
#pragma unroll
        for (int it = 0; it < 2; ++it) {
            int c = it * 256 + w * 64 + lane;
            glds16(Bbase + (size_t)(c >> 2) * K + k0 + (c & 3) * 8,
                   &Bs[(it * 256 + w * 64) * 8]);
        }
#pragma unroll
        for (int it = 0; it < 2; ++it) {
            int c = it * 256 + w * 64 + lane;
            glds16(A16 + (size_t)(mb * 128 + (c >> 2)) * K + k0 + (c & 3) * 8,
                   &As[(it * 256 + w * 64) * 8]);
        }
        __syncthreads();
        f16x8 af[4], bf[4];
#pragma unroll
        for (int mt = 0; mt < 4; ++mt)
            af[mt] = *(const f16x8*)&As[(wm * 64 + mt * 16 + cl) * 32 + q * 8];
#pragma unroll
        for (int nt = 0; nt < 4; ++nt)
            bf[nt] = *(const f16x8*)&Bs[(wn * 64 + nt * 16 + cl) * 32 + q * 8];
#pragma unroll
        for (int mt = 0; mt < 4; ++mt)
#pragma unroll
            for (int nt = 0; nt < 4; ++nt)
                acc[mt][nt] = MFMA16(af[mt], bf[nt], acc[mt][nt]);
        __syncthreads();
    }
    float bv[4];
#pragma unroll
    for (int nt = 0; nt < 4; ++nt) bv[nt] = bias[nb * 128 + wn * 64 + nt * 16 + cl];
#pragma unroll
    for (int mt = 0; mt < 4; ++mt) {
#pragma unroll
        for (int nt = 0; nt < 4; ++nt) {
            size_t gr = (size_t)(mb * 128 + wm * 64 + mt * 16 + q * 4);
            int gc = nb * 128 + wn * 64 + nt * 16 + cl;
#pragma unroll
            for (int r = 0; r < 4; ++r) {
                float v = acc[mt][nt][r] + bv[nt];
                if (OUT_F16)
                    ((f16*)C_)[(gr + r) * N + gc] = (f16)v;
                else
                    ((float*)C_)[(gr + r) * N + gc] = v;
            }
        }
    }
}

// ---------------- segment-average partials ----------------
__global__ __launch_bounds__(256) void avg_kernel(const f16* __restrict__ X1h,
                                                  float* __restrict__ partial) {
    const int bn = blockIdx.x >> 2, rc = blockIdx.x & 3;
    const int tid = threadIdx.x;
    const f16* base = X1h + (size_t)bn * 262144 + (size_t)rc * 65536 + tid * 4;
    float s0 = 0.f, s1 = 0.f, s2 = 0.f, s3 = 0.f;
    for (int l = 0; l < 64; ++l) {
        f16x4 v = *(const f16x4*)(base + (size_t)l * 1024);
        s0 += (float)v[0]; s1 += (float)v[1]; s2 += (float)v[2]; s3 += (float)v[3];
    }
    const float sc = 1.f / 256.f;
    float4 o = make_float4(s0 * sc, s1 * sc, s2 * sc, s3 * sc);
    *(float4*)(partial + (size_t)(bn * 4 + rc) * 1024 + tid * 4) = o;
}

// ---------------- router ----------------
__global__ __launch_bounds__(64) void router_kernel(const float* __restrict__ partial,
                                                    const float* __restrict__ emb,
                                                    float* __restrict__ ew) {
    const int t = blockIdx.x;
    const int bn = t >> 3, h = t & 7;
    const int lane = threadIdx.x;
    float acc = 0.f;
    const float* p = partial + (size_t)bn * 4096 + h * 128;
    if (lane < 16) {
        for (int d = 0; d < 128; ++d) {
            float a = p[d] + p[d + 1024] + p[d + 2048] + p[d + 3072];
            acc = fmaf(a, emb[d * 16 + lane], acc);
        }
    }
    float m = acc;
#pragma unroll
    for (int o = 8; o; o >>= 1) m = fmaxf(m, __shfl_xor(m, o));
    float pr = __expf(acc - m);
    float s = pr;
#pragma unroll
    for (int o = 8; o; o >>= 1) s += __shfl_xor(s, o);
    if (lane < 16) ew[t * 16 + lane] = pr / s;
}

// ---------------- expert mixture (pk_fma version) ----------------
__global__ __launch_bounds__(256) void mix_kernel(const float* __restrict__ ew,
                                                  const float* __restrict__ FL,
                                                  const float* __restrict__ SL,
                                                  f16* __restrict__ m1h,
                                                  f16* __restrict__ m2h) {
    __shared__ f32x2 ews2[4096];  // [tt][e] duplicated {w,w}, 32KB
    const int bid = blockIdx.x;
    const int which = bid >> 8, th = (bid >> 7) & 1, chunk = bid & 127;
    const float* src = which ? SL : FL;
    f16* dst = which ? m2h : m1h;
    const int tid = threadIdx.x;
    const int e0 = chunk * 512 + tid * 2;
    f32x2 fl[16];
#pragma unroll
    for (int e = 0; e < 16; ++e)
        fl[e] = *(const f32x2*)(src + (size_t)e * 65536 + e0);
    for (int i = tid; i < 4096; i += 256) {
        float wv = ew[th * 4096 + i];
        f32x2 p; p.x = wv; p.y = wv;
        ews2[i] = p;
    }
    __syncthreads();
#pragma unroll 1
    for (int tt = 0; tt < 256; ++tt) {
        f32x2 a; a.x = 0.f; a.y = 0.f;
#pragma unroll
        for (int e = 0; e < 16; ++e)
            a = pk_fma(ews2[tt * 16 + e], fl[e], a);
        f16x2 h;
        h[0] = (f16)a.x; h[1] = (f16)a.y;
        *(f16x2*)(dst + (size_t)(th * 256 + tt) * 65536 + e0) = h;
    }
}

// ---------------- MLP: LDS-streamed weights ----------------
__device__ __forceinline__ void stage_w128(const f16* __restrict__ src, f16* lds,
                                           int w, int lane, int rowstride) {
#pragma unroll
    for (int it = 0; it < 8; ++it) {
        int cbase = it * 256 + w * 64;
        int c = cbase + lane;
        int row = c >> 4, pc = c & 15;
        int lc = pc ^ (row & 7);
        glds16(src + (size_t)row * rowstride + lc * 8, lds + cbase * 8);
    }
}

__global__ __launch_bounds__(256) void mlp_kernel(const f16* __restrict__ Xg,
                                                  const f16* __restrict__ m1h,
                                                  const f16* __restrict__ m2h,
                                                  f16* __restrict__ Yg) {
    __shared__ f16 Hs[128 * 128];
    __shared__ f16 Ws[128 * 128];
    // XCD swizzle over 1024 blocks (= 512 tiles x 2 halves): lh pair colocates
    const int cpx = (int)gridDim.x >> 3;
    const int logical = ((int)blockIdx.x & 7) * cpx + ((int)blockIdx.x >> 3);
    const int t = logical >> 1, lh = logical & 1;
    const int n = (t >> 3) & 15;
    const int tm = (n > 0) ? (t - 8) : t;
    const int tid = threadIdx.x;
    const int lane = tid & 63, w = tid >> 6;
    const int q = lane >> 4, cl = lane & 15;
    const int l0 = w * 32;

    const f16* Xsrc = Xg + (size_t)t * 32768 + lh * 16384;
    const f16* m1b = m1h + (size_t)tm * 65536;
    const f16* m2b = m2h + (size_t)tm * 65536;

    f16x8 xf[2][4];
#pragma unroll
    for (int lt = 0; lt < 2; ++lt) {
        int l = l0 + lt * 16 + cl;
#pragma unroll
        for (int ks = 0; ks < 4; ++ks)
            xf[lt][ks] = *(const f16x8*)(Xsrc + (size_t)l * 128 + ks * 32 + q * 8);
    }
    stage_w128(m1b, Ws, w, lane, 128);
    __syncthreads();

    f32x4 acc2[2][8] = {};
#pragma unroll 1
    for (int ic = 0; ic < 4; ++ic) {
        // ---- stage1: h^T over i-chunk, Ws = m1[ic] ----
#pragma unroll
        for (int it = 0; it < 8; ++it) {
            f16x8 af[4];
#pragma unroll
            for (int ks = 0; ks < 4; ++ks) {
                int r = it * 16 + cl;
                int ch = (ks * 4 + q) ^ (r & 7);
                af[ks] = *(const f16x8*)&Ws[r * 128 + ch * 8];
            }
            f32x4 a1[2] = {};
#pragma unroll
            for (int ks = 0; ks < 4; ++ks)
#pragma unroll
                for (int lt = 0; lt < 2; ++lt)
                    a1[lt] = MFMA16(af[ks], xf[lt][ks], a1[lt]);
            int ibase = it * 16 + q * 4;
            int ch = ibase >> 3;
            int sub = (q & 1) * 8;
#pragma unroll
            for (int lt = 0; lt < 2; ++lt) {
                int l = l0 + lt * 16 + cl;
                f16x4 hv;
                hv[0] = (f16)fmaxf(a1[lt][0], 0.f);
                hv[1] = (f16)fmaxf(a1[lt][1], 0.f);
                hv[2] = (f16)fmaxf(a1[lt][2], 0.f);
                hv[3] = (f16)fmaxf(a1[lt][3], 0.f);
                *(f16x4*)((char*)Hs + (size_t)l * 256 + ((ch ^ (l & 7)) << 4) + sub) = hv;
            }
        }
        __syncthreads();
        stage_w128(m2b + ic * 128, Ws, w, lane, 512);
        __syncthreads();

        // ---- stage2: acc2 += h @ m2[ic]^T ----
        f16x8 hf[2][4];
#pragma unroll
        for (int lt = 0; lt < 2; ++lt) {
            int l = l0 + lt * 16 + cl;
#pragma unroll
            for (int ks = 0; ks < 4; ++ks) {
                int ch = (ks * 4 + q) ^ (l & 7);
                hf[lt][ks] = *(const f16x8*)&Hs[l * 128 + ch * 8];
            }
        }
#pragma unroll
        for (int nt = 0; nt < 8; ++nt) {
            f16x8 bf[4];
#pragma unroll
            for (int ks = 0; ks < 4; ++ks) {
                int r = nt * 16 + cl;
                int ch = (ks * 4 + q) ^ (r & 7);
                bf[ks] = *(const f16x8*)&Ws[r * 128 + ch * 8];
            }
#pragma unroll
            for (int lt = 0; lt < 2; ++lt)
#pragma unroll
                for (int ks = 0; ks < 4; ++ks)
                    acc2[lt][nt] = MFMA16(hf[lt][ks], bf[ks], acc2[lt][nt]);
        }
        __syncthreads();
        if (ic < 3) {
            stage_w128(m1b + (size_t)(ic + 1) * 16384, Ws, w, lane, 128);
            __syncthreads();
        }
    }
    f16* Yb = Yg + (size_t)t * 32768 + lh * 16384;
#pragma unroll
    for (int lt = 0; lt < 2; ++lt) {
#pragma unroll
        for (int nt = 0; nt < 8; ++nt) {
            int lr = l0 + lt * 16 + q * 4;
            int d = nt * 16 + cl;
#pragma unroll
            for (int r = 0; r < 4; ++r)
                Yb[(size_t)(lr + r) * 128 + d] = (f16)acc2[lt][nt][r];
        }
    }
}

extern "C" void kernel_launch(void* const* d_in, const int* in_sizes, int n_in,
                              void* d_out, int out_size, void* d_ws, size_t ws_size,
                              hipStream_t stream) {
    const float* x    = (const float*)d_in[0];
    const float* W_mh = (const float*)d_in[1];
    const float* b_mh = (const float*)d_in[2];
    const float* W_mg = (const float*)d_in[3];
    const float* b_mg = (const float*)d_in[4];
    const float* emb  = (const float*)d_in[5];
    const float* FL   = (const float*)d_in[6];
    const float* SL   = (const float*)d_in[7];

    char* ws = (char*)d_ws;
    f16*   X1h  = (f16*)(ws + 0);
    f16*   m1h  = (f16*)(ws + 33554432);
    f16*   X0h  = (f16*)(ws + 33554432);   // aliases m1h: dead after gemm1,
                                           // m1h written later by mix_kernel
    f16*   m2h  = (f16*)(ws + 100663296);
    f16*   Wmhh = (f16*)(ws + 167772160);
    f16*   Wmgh = (f16*)(ws + 169869312);
    float* part = (float*)(ws + 171966464);
    float* ew   = (float*)(ws + 173015040);

    cvt_kernel<<<512, 256, 0, stream>>>(W_mh, Wmhh, 1048576);
    cvt_kernel<<<512, 256, 0, stream>>>(W_mg, Wmgh, 1048576);
    cvt_kernel<<<8192, 256, 0, stream>>>(x, X0h, 16777216);
    gemm_bt_kernel<true><<<1024, 256, 0, stream>>>(X0h, Wmhh, b_mh, X1h,
                                                   16384, 1024, 1024);
    avg_kernel<<<256, 256, 0, stream>>>(X1h, part);
    router_kernel<<<512, 64, 0, stream>>>(part, emb, ew);
    mix_kernel<<<512, 256, 0, stream>>>(ew, FL, SL, m1h, m2h);
    mlp_kernel<<<1024, 256, 0, stream>>>(X1h, m1h, m2h, X1h);
    gemm_bt_kernel<false><<<1024, 256, 0, stream>>>(X1h, Wmgh, b_mg, d_out,
                                                    16384, 1024, 1024);
}

// Round 7
// 237.811 us; speedup vs baseline: 1.2644x; 1.1316x over previous
//
#include <hip/hip_runtime.h>
#include <hip/hip_bf16.h>

typedef _Float16 f16;
typedef f16 f16x2 __attribute__((ext_vector_type(2)));
typedef f16 f16x4 __attribute__((ext_vector_type(4)));
typedef f16 f16x8 __attribute__((ext_vector_type(8)));
typedef float f32x2 __attribute__((ext_vector_type(2)));
typedef float f32x4 __attribute__((ext_vector_type(4)));

#define MFMA16(a, b, c) __builtin_amdgcn_mfma_f32_16x16x32_f16(a, b, c, 0, 0, 0)

__device__ __forceinline__ void glds16(const void* g, void* l) {
    __builtin_amdgcn_global_load_lds(
        (const __attribute__((address_space(1))) unsigned int*)g,
        (__attribute__((address_space(3))) unsigned int*)l, 16, 0, 0);
}

// ---------------- f32 -> f16 convert ----------------
__global__ __launch_bounds__(256) void cvt_kernel(const float* __restrict__ s,
                                                  f16* __restrict__ d, int n) {
    int i = (blockIdx.x * 256 + threadIdx.x) * 8;
    if (i >= n) return;
    float4 a = *(const float4*)(s + i);
    float4 b = *(const float4*)(s + i + 4);
    f16x8 h;
    h[0] = (f16)a.x; h[1] = (f16)a.y; h[2] = (f16)a.z; h[3] = (f16)a.w;
    h[4] = (f16)b.x; h[5] = (f16)b.y; h[6] = (f16)b.z; h[7] = (f16)b.w;
    *(f16x8*)(d + i) = h;
}

// ---------------- GEMM: C[M,N] = A[M,K] @ B[N,K]^T + bias ----------------
// R4-proven structure: 128x128 tile, BK=32, 4 waves (2x2), single-buffer LDS,
// 2 barriers/iter, glds16 staging both operands, XCD-swizzled blockIdx.
template <bool OUT_F16>
__global__ __launch_bounds__(256) void gemm_bt_kernel(
    const f16* __restrict__ A16, const f16* __restrict__ Bw,
    const float* __restrict__ bias, void* __restrict__ C_, int M, int N, int K) {
    __shared__ f16 As[128 * 32];
    __shared__ f16 Bs[128 * 32];
    const int tid = threadIdx.x;
    const int lane = tid & 63;
    const int w = tid >> 6;
    const int nblk = N >> 7;
    const int cpx = (int)gridDim.x >> 3;
    const int logical = ((int)blockIdx.x & 7) * cpx + ((int)blockIdx.x >> 3);
    const int mb = logical / nblk, nb = logical % nblk;
    const int wm = w >> 1, wn = w & 1;
    const int q = lane >> 4, cl = lane & 15;

    const f16* Bbase = Bw + (size_t)nb * 128 * K;

    f32x4 acc[4][4] = {};

#pragma unroll 1
    for (int kt = 0; kt < (K >> 5); ++kt) {
        const int k0 = kt << 5;
#pragma unroll
        for (int it = 0; it < 2; ++it) {
            int c = it * 256 + w * 64 + lane;
            glds16(Bbase + (size_t)(c >> 2) * K + k0 + (c & 3) * 8,
                   &Bs[(it * 256 + w * 64) * 8]);
        }
#pragma unroll
        for (int it = 0; it < 2; ++it) {
            int c = it * 256 + w * 64 + lane;
            glds16(A16 + (size_t)(mb * 128 + (c >> 2)) * K + k0 + (c & 3) * 8,
                   &As[(it * 256 + w * 64) * 8]);
        }
        __syncthreads();
        f16x8 af[4], bf[4];
#pragma unroll
        for (int mt = 0; mt < 4; ++mt)
            af[mt] = *(const f16x8*)&As[(wm * 64 + mt * 16 + cl) * 32 + q * 8];
#pragma unroll
        for (int nt = 0; nt < 4; ++nt)
            bf[nt] = *(const f16x8*)&Bs[(wn * 64 + nt * 16 + cl) * 32 + q * 8];
#pragma unroll
        for (int mt = 0; mt < 4; ++mt)
#pragma unroll
            for (int nt = 0; nt < 4; ++nt)
                acc[mt][nt] = MFMA16(af[mt], bf[nt], acc[mt][nt]);
        __syncthreads();
    }
    float bv[4];
#pragma unroll
    for (int nt = 0; nt < 4; ++nt) bv[nt] = bias[nb * 128 + wn * 64 + nt * 16 + cl];
#pragma unroll
    for (int mt = 0; mt < 4; ++mt) {
#pragma unroll
        for (int nt = 0; nt < 4; ++nt) {
            size_t gr = (size_t)(mb * 128 + wm * 64 + mt * 16 + q * 4);
            int gc = nb * 128 + wn * 64 + nt * 16 + cl;
#pragma unroll
            for (int r = 0; r < 4; ++r) {
                float v = acc[mt][nt][r] + bv[nt];
                if (OUT_F16)
                    ((f16*)C_)[(gr + r) * N + gc] = (f16)v;
                else
                    ((float*)C_)[(gr + r) * N + gc] = v;
            }
        }
    }
}

// ---------------- segment-average partials ----------------
__global__ __launch_bounds__(256) void avg_kernel(const f16* __restrict__ X1h,
                                                  float* __restrict__ partial) {
    const int bn = blockIdx.x >> 2, rc = blockIdx.x & 3;
    const int tid = threadIdx.x;
    const f16* base = X1h + (size_t)bn * 262144 + (size_t)rc * 65536 + tid * 4;
    float s0 = 0.f, s1 = 0.f, s2 = 0.f, s3 = 0.f;
    for (int l = 0; l < 64; ++l) {
        f16x4 v = *(const f16x4*)(base + (size_t)l * 1024);
        s0 += (float)v[0]; s1 += (float)v[1]; s2 += (float)v[2]; s3 += (float)v[3];
    }
    const float sc = 1.f / 256.f;
    float4 o = make_float4(s0 * sc, s1 * sc, s2 * sc, s3 * sc);
    *(float4*)(partial + (size_t)(bn * 4 + rc) * 1024 + tid * 4) = o;
}

// ---------------- router ----------------
__global__ __launch_bounds__(64) void router_kernel(const float* __restrict__ partial,
                                                    const float* __restrict__ emb,
                                                    float* __restrict__ ew) {
    const int t = blockIdx.x;
    const int bn = t >> 3, h = t & 7;
    const int lane = threadIdx.x;
    float acc = 0.f;
    const float* p = partial + (size_t)bn * 4096 + h * 128;
    if (lane < 16) {
        for (int d = 0; d < 128; ++d) {
            float a = p[d] + p[d + 1024] + p[d + 2048] + p[d + 3072];
            acc = fmaf(a, emb[d * 16 + lane], acc);
        }
    }
    float m = acc;
#pragma unroll
    for (int o = 8; o; o >>= 1) m = fmaxf(m, __shfl_xor(m, o));
    float pr = __expf(acc - m);
    float s = pr;
#pragma unroll
    for (int o = 8; o; o >>= 1) s += __shfl_xor(s, o);
    if (lane < 16) ew[t * 16 + lane] = pr / s;
}

// ---------------- expert mixture v3: SGPR weights, no LDS ----------------
// grid 2048 = which(2) x tgroup(16, 32 tiles each) x chunk(64, 1024 elems).
// Thread owns 4 consecutive f32 elements of 16 experts in regs (64 VGPR).
// Per tile: 16 block-uniform weights (scalarized loads) + 64 v_fmac + 8B store.
__global__ __launch_bounds__(256) void mix_kernel(const float* __restrict__ ew,
                                                  const float* __restrict__ FL,
                                                  const float* __restrict__ SL,
                                                  f16* __restrict__ m1h,
                                                  f16* __restrict__ m2h) {
    const int bid = blockIdx.x;
    const int which = bid >> 10;
    const int tg = (bid >> 6) & 15;
    const int chunk = bid & 63;
    const float* src = which ? SL : FL;
    f16* dst = which ? m2h : m1h;
    const int tid = threadIdx.x;
    const int e0 = chunk * 1024 + tid * 4;

    f32x4 fl[16];
#pragma unroll
    for (int e = 0; e < 16; ++e)
        fl[e] = *(const f32x4*)(src + (size_t)e * 65536 + e0);

    const float* wbase = ew + (size_t)tg * 32 * 16;
    float wc[16];
#pragma unroll
    for (int e = 0; e < 16; ++e) wc[e] = wbase[e];

#pragma unroll 1
    for (int tt = 0; tt < 32; ++tt) {
        float wn[16];
        if (tt < 31) {
#pragma unroll
            for (int e = 0; e < 16; ++e) wn[e] = wbase[(tt + 1) * 16 + e];
        }
        f32x4 a = {0.f, 0.f, 0.f, 0.f};
#pragma unroll
        for (int e = 0; e < 16; ++e) {
            a[0] = fmaf(wc[e], fl[e][0], a[0]);
            a[1] = fmaf(wc[e], fl[e][1], a[1]);
            a[2] = fmaf(wc[e], fl[e][2], a[2]);
            a[3] = fmaf(wc[e], fl[e][3], a[3]);
        }
        f16x4 h;
        h[0] = (f16)a[0]; h[1] = (f16)a[1]; h[2] = (f16)a[2]; h[3] = (f16)a[3];
        *(f16x4*)(dst + (size_t)(tg * 32 + tt) * 65536 + e0) = h;
        if (tt < 31) {
#pragma unroll
            for (int e = 0; e < 16; ++e) wc[e] = wn[e];
        }
    }
}

// ---------------- MLP: LDS-streamed weights ----------------
__device__ __forceinline__ void stage_w128(const f16* __restrict__ src, f16* lds,
                                           int w, int lane, int rowstride) {
#pragma unroll
    for (int it = 0; it < 8; ++it) {
        int cbase = it * 256 + w * 64;
        int c = cbase + lane;
        int row = c >> 4, pc = c & 15;
        int lc = pc ^ (row & 7);
        glds16(src + (size_t)row * rowstride + lc * 8, lds + cbase * 8);
    }
}

__global__ __launch_bounds__(256) void mlp_kernel(const f16* __restrict__ Xg,
                                                  const f16* __restrict__ m1h,
                                                  const f16* __restrict__ m2h,
                                                  f16* __restrict__ Yg) {
    __shared__ f16 Hs[128 * 128];
    __shared__ f16 Ws[128 * 128];
    // XCD swizzle over 1024 blocks (= 512 tiles x 2 halves): lh pair colocates
    const int cpx = (int)gridDim.x >> 3;
    const int logical = ((int)blockIdx.x & 7) * cpx + ((int)blockIdx.x >> 3);
    const int t = logical >> 1, lh = logical & 1;
    const int n = (t >> 3) & 15;
    const int tm = (n > 0) ? (t - 8) : t;
    const int tid = threadIdx.x;
    const int lane = tid & 63, w = tid >> 6;
    const int q = lane >> 4, cl = lane & 15;
    const int l0 = w * 32;

    const f16* Xsrc = Xg + (size_t)t * 32768 + lh * 16384;
    const f16* m1b = m1h + (size_t)tm * 65536;
    const f16* m2b = m2h + (size_t)tm * 65536;

    f16x8 xf[2][4];
#pragma unroll
    for (int lt = 0; lt < 2; ++lt) {
        int l = l0 + lt * 16 + cl;
#pragma unroll
        for (int ks = 0; ks < 4; ++ks)
            xf[lt][ks] = *(const f16x8*)(Xsrc + (size_t)l * 128 + ks * 32 + q * 8);
    }
    stage_w128(m1b, Ws, w, lane, 128);
    __syncthreads();

    f32x4 acc2[2][8] = {};
#pragma unroll 1
    for (int ic = 0; ic < 4; ++ic) {
        // ---- stage1: h^T over i-chunk, Ws = m1[ic] ----
#pragma unroll
        for (int it = 0; it < 8; ++it) {
            f16x8 af[4];
#pragma unroll
            for (int ks = 0; ks < 4; ++ks) {
                int r = it * 16 + cl;
                int ch = (ks * 4 + q) ^ (r & 7);
                af[ks] = *(const f16x8*)&Ws[r * 128 + ch * 8];
            }
            f32x4 a1[2] = {};
#pragma unroll
            for (int ks = 0; ks < 4; ++ks)
#pragma unroll
                for (int lt = 0; lt < 2; ++lt)
                    a1[lt] = MFMA16(af[ks], xf[lt][ks], a1[lt]);
            int ibase = it * 16 + q * 4;
            int ch = ibase >> 3;
            int sub = (q & 1) * 8;
#pragma unroll
            for (int lt = 0; lt < 2; ++lt) {
                int l = l0 + lt * 16 + cl;
                f16x4 hv;
                hv[0] = (f16)fmaxf(a1[lt][0], 0.f);
                hv[1] = (f16)fmaxf(a1[lt][1], 0.f);
                hv[2] = (f16)fmaxf(a1[lt][2], 0.f);
                hv[3] = (f16)fmaxf(a1[lt][3], 0.f);
                *(f16x4*)((char*)Hs + (size_t)l * 256 + ((ch ^ (l & 7)) << 4) + sub) = hv;
            }
        }
        __syncthreads();
        stage_w128(m2b + ic * 128, Ws, w, lane, 512);
        __syncthreads();

        // ---- stage2: acc2 += h @ m2[ic]^T ----
        f16x8 hf[2][4];
#pragma unroll
        for (int lt = 0; lt < 2; ++lt) {
            int l = l0 + lt * 16 + cl;
#pragma unroll
            for (int ks = 0; ks < 4; ++ks) {
                int ch = (ks * 4 + q) ^ (l & 7);
                hf[lt][ks] = *(const f16x8*)&Hs[l * 128 + ch * 8];
            }
        }
#pragma unroll
        for (int nt = 0; nt < 8; ++nt) {
            f16x8 bf[4];
#pragma unroll
            for (int ks = 0; ks < 4; ++ks) {
                int r = nt * 16 + cl;
                int ch = (ks * 4 + q) ^ (r & 7);
                bf[ks] = *(const f16x8*)&Ws[r * 128 + ch * 8];
            }
#pragma unroll
            for (int lt = 0; lt < 2; ++lt)
#pragma unroll
                for (int ks = 0; ks < 4; ++ks)
                    acc2[lt][nt] = MFMA16(hf[lt][ks], bf[ks], acc2[lt][nt]);
        }
        __syncthreads();
        if (ic < 3) {
            stage_w128(m1b + (size_t)(ic + 1) * 16384, Ws, w, lane, 128);
            __syncthreads();
        }
    }
    f16* Yb = Yg + (size_t)t * 32768 + lh * 16384;
#pragma unroll
    for (int lt = 0; lt < 2; ++lt) {
#pragma unroll
        for (int nt = 0; nt < 8; ++nt) {
            int lr = l0 + lt * 16 + q * 4;
            int d = nt * 16 + cl;
#pragma unroll
            for (int r = 0; r < 4; ++r)
                Yb[(size_t)(lr + r) * 128 + d] = (f16)acc2[lt][nt][r];
        }
    }
}

extern "C" void kernel_launch(void* const* d_in, const int* in_sizes, int n_in,
                              void* d_out, int out_size, void* d_ws, size_t ws_size,
                              hipStream_t stream) {
    const float* x    = (const float*)d_in[0];
    const float* W_mh = (const float*)d_in[1];
    const float* b_mh = (const float*)d_in[2];
    const float* W_mg = (const float*)d_in[3];
    const float* b_mg = (const float*)d_in[4];
    const float* emb  = (const float*)d_in[5];
    const float* FL   = (const float*)d_in[6];
    const float* SL   = (const float*)d_in[7];

    char* ws = (char*)d_ws;
    f16*   X1h  = (f16*)(ws + 0);
    f16*   m1h  = (f16*)(ws + 33554432);
    f16*   X0h  = (f16*)(ws + 33554432);   // aliases m1h: dead after gemm1,
                                           // m1h written later by mix_kernel
    f16*   m2h  = (f16*)(ws + 100663296);
    f16*   Wmhh = (f16*)(ws + 167772160);
    f16*   Wmgh = (f16*)(ws + 169869312);
    float* part = (float*)(ws + 171966464);
    float* ew   = (float*)(ws + 173015040);

    cvt_kernel<<<512, 256, 0, stream>>>(W_mh, Wmhh, 1048576);
    cvt_kernel<<<512, 256, 0, stream>>>(W_mg, Wmgh, 1048576);
    cvt_kernel<<<8192, 256, 0, stream>>>(x, X0h, 16777216);
    gemm_bt_kernel<true><<<1024, 256, 0, stream>>>(X0h, Wmhh, b_mh, X1h,
                                                   16384, 1024, 1024);
    avg_kernel<<<256, 256, 0, stream>>>(X1h, part);
    router_kernel<<<512, 64, 0, stream>>>(part, emb, ew);
    mix_kernel<<<2048, 256, 0, stream>>>(ew, FL, SL, m1h, m2h);
    mlp_kernel<<<1024, 256, 0, stream>>>(X1h, m1h, m2h, X1h);
    gemm_bt_kernel<false><<<1024, 256, 0, stream>>>(X1h, Wmgh, b_mg, d_out,
                                                    16384, 1024, 1024);
}

// Round 8
// 235.948 us; speedup vs baseline: 1.2744x; 1.0079x over previous
//
#include <hip/hip_runtime.h>
#include <hip/hip_bf16.h>

typedef _Float16 f16;
typedef f16 f16x2 __attribute__((ext_vector_type(2)));
typedef f16 f16x4 __attribute__((ext_vector_type(4)));
typedef f16 f16x8 __attribute__((ext_vector_type(8)));
typedef float f32x2 __attribute__((ext_vector_type(2)));
typedef float f32x4 __attribute__((ext_vector_type(4)));

#define MFMA16(a, b, c) __builtin_amdgcn_mfma_f32_16x16x32_f16(a, b, c, 0, 0, 0)

__device__ __forceinline__ void glds16(const void* g, void* l) {
    __builtin_amdgcn_global_load_lds(
        (const __attribute__((address_space(1))) unsigned int*)g,
        (__attribute__((address_space(3))) unsigned int*)l, 16, 0, 0);
}

// ---------------- f32 -> f16 convert ----------------
__global__ __launch_bounds__(256) void cvt_kernel(const float* __restrict__ s,
                                                  f16* __restrict__ d, int n) {
    int i = (blockIdx.x * 256 + threadIdx.x) * 8;
    if (i >= n) return;
    float4 a = *(const float4*)(s + i);
    float4 b = *(const float4*)(s + i + 4);
    f16x8 h;
    h[0] = (f16)a.x; h[1] = (f16)a.y; h[2] = (f16)a.z; h[3] = (f16)a.w;
    h[4] = (f16)b.x; h[5] = (f16)b.y; h[6] = (f16)b.z; h[7] = (f16)b.w;
    *(f16x8*)(d + i) = h;
}

// ---------------- GEMM: C[M,N] = A[M,K] @ B[N,K]^T + bias ----------------
// 128x128 tile, BK=32, 4 waves (2x2), glds16 staging, XCD-swizzled blockIdx.
// T2 LDS swizzle: granule g at (row) holds global granule g^((row>>1)&3).
// Read group = (row*4 + q^((row>>1)&3))%8 covers all 8 bank-groups per 8 rows
// -> 2-way (free) instead of 8-way. Source pre-swizzled (dest linear, rule 21).
template <bool OUT_F16>
__global__ __launch_bounds__(256) void gemm_bt_kernel(
    const f16* __restrict__ A16, const f16* __restrict__ Bw,
    const float* __restrict__ bias, void* __restrict__ C_, int M, int N, int K) {
    __shared__ f16 As[128 * 32];
    __shared__ f16 Bs[128 * 32];
    const int tid = threadIdx.x;
    const int lane = tid & 63;
    const int w = tid >> 6;
    const int nblk = N >> 7;
    const int cpx = (int)gridDim.x >> 3;
    const int logical = ((int)blockIdx.x & 7) * cpx + ((int)blockIdx.x >> 3);
    const int mb = logical / nblk, nb = logical % nblk;
    const int wm = w >> 1, wn = w & 1;
    const int q = lane >> 4, cl = lane & 15;

    const f16* Bbase = Bw + (size_t)nb * 128 * K;

    // staging: row/granule per lane, swizzled source granule (loop-invariant)
    int srow[2], sg[2];
#pragma unroll
    for (int it = 0; it < 2; ++it) {
        int c = it * 256 + w * 64 + lane;
        srow[it] = c >> 2;
        sg[it] = (c & 3) ^ ((srow[it] >> 1) & 3);
    }
    // fragment-read granule swizzle (per-thread constant)
    const int qs = q ^ ((cl >> 1) & 3);

    f32x4 acc[4][4] = {};

#pragma unroll 1
    for (int kt = 0; kt < (K >> 5); ++kt) {
        const int k0 = kt << 5;
#pragma unroll
        for (int it = 0; it < 2; ++it) {
            glds16(Bbase + (size_t)srow[it] * K + k0 + sg[it] * 8,
                   &Bs[(it * 256 + w * 64) * 8]);
        }
#pragma unroll
        for (int it = 0; it < 2; ++it) {
            glds16(A16 + (size_t)(mb * 128 + srow[it]) * K + k0 + sg[it] * 8,
                   &As[(it * 256 + w * 64) * 8]);
        }
        __syncthreads();
        f16x8 af[4], bf[4];
#pragma unroll
        for (int mt = 0; mt < 4; ++mt)
            af[mt] = *(const f16x8*)&As[(wm * 64 + mt * 16 + cl) * 32 + qs * 8];
#pragma unroll
        for (int nt = 0; nt < 4; ++nt)
            bf[nt] = *(const f16x8*)&Bs[(wn * 64 + nt * 16 + cl) * 32 + qs * 8];
#pragma unroll
        for (int mt = 0; mt < 4; ++mt)
#pragma unroll
            for (int nt = 0; nt < 4; ++nt)
                acc[mt][nt] = MFMA16(af[mt], bf[nt], acc[mt][nt]);
        __syncthreads();
    }
    float bv[4];
#pragma unroll
    for (int nt = 0; nt < 4; ++nt) bv[nt] = bias[nb * 128 + wn * 64 + nt * 16 + cl];
#pragma unroll
    for (int mt = 0; mt < 4; ++mt) {
#pragma unroll
        for (int nt = 0; nt < 4; ++nt) {
            size_t gr = (size_t)(mb * 128 + wm * 64 + mt * 16 + q * 4);
            int gc = nb * 128 + wn * 64 + nt * 16 + cl;
#pragma unroll
            for (int r = 0; r < 4; ++r) {
                float v = acc[mt][nt][r] + bv[nt];
                if (OUT_F16)
                    ((f16*)C_)[(gr + r) * N + gc] = (f16)v;
                else
                    ((float*)C_)[(gr + r) * N + gc] = v;
            }
        }
    }
}

// ---------------- segment-average partials ----------------
__global__ __launch_bounds__(256) void avg_kernel(const f16* __restrict__ X1h,
                                                  float* __restrict__ partial) {
    const int bn = blockIdx.x >> 2, rc = blockIdx.x & 3;
    const int tid = threadIdx.x;
    const f16* base = X1h + (size_t)bn * 262144 + (size_t)rc * 65536 + tid * 4;
    float s0 = 0.f, s1 = 0.f, s2 = 0.f, s3 = 0.f;
    for (int l = 0; l < 64; ++l) {
        f16x4 v = *(const f16x4*)(base + (size_t)l * 1024);
        s0 += (float)v[0]; s1 += (float)v[1]; s2 += (float)v[2]; s3 += (float)v[3];
    }
    const float sc = 1.f / 256.f;
    float4 o = make_float4(s0 * sc, s1 * sc, s2 * sc, s3 * sc);
    *(float4*)(partial + (size_t)(bn * 4 + rc) * 1024 + tid * 4) = o;
}

// ---------------- router ----------------
__global__ __launch_bounds__(64) void router_kernel(const float* __restrict__ partial,
                                                    const float* __restrict__ emb,
                                                    float* __restrict__ ew) {
    const int t = blockIdx.x;
    const int bn = t >> 3, h = t & 7;
    const int lane = threadIdx.x;
    float acc = 0.f;
    const float* p = partial + (size_t)bn * 4096 + h * 128;
    if (lane < 16) {
        for (int d = 0; d < 128; ++d) {
            float a = p[d] + p[d + 1024] + p[d + 2048] + p[d + 3072];
            acc = fmaf(a, emb[d * 16 + lane], acc);
        }
    }
    float m = acc;
#pragma unroll
    for (int o = 8; o; o >>= 1) m = fmaxf(m, __shfl_xor(m, o));
    float pr = __expf(acc - m);
    float s = pr;
#pragma unroll
    for (int o = 8; o; o >>= 1) s += __shfl_xor(s, o);
    if (lane < 16) ew[t * 16 + lane] = pr / s;
}

// ---------------- expert mixture v3: SGPR weights, no LDS ----------------
__global__ __launch_bounds__(256) void mix_kernel(const float* __restrict__ ew,
                                                  const float* __restrict__ FL,
                                                  const float* __restrict__ SL,
                                                  f16* __restrict__ m1h,
                                                  f16* __restrict__ m2h) {
    const int bid = blockIdx.x;
    const int which = bid >> 10;
    const int tg = (bid >> 6) & 15;
    const int chunk = bid & 63;
    const float* src = which ? SL : FL;
    f16* dst = which ? m2h : m1h;
    const int tid = threadIdx.x;
    const int e0 = chunk * 1024 + tid * 4;

    f32x4 fl[16];
#pragma unroll
    for (int e = 0; e < 16; ++e)
        fl[e] = *(const f32x4*)(src + (size_t)e * 65536 + e0);

    const float* wbase = ew + (size_t)tg * 32 * 16;
    float wc[16];
#pragma unroll
    for (int e = 0; e < 16; ++e) wc[e] = wbase[e];

#pragma unroll 1
    for (int tt = 0; tt < 32; ++tt) {
        float wn[16];
        if (tt < 31) {
#pragma unroll
            for (int e = 0; e < 16; ++e) wn[e] = wbase[(tt + 1) * 16 + e];
        }
        f32x4 a = {0.f, 0.f, 0.f, 0.f};
#pragma unroll
        for (int e = 0; e < 16; ++e) {
            a[0] = fmaf(wc[e], fl[e][0], a[0]);
            a[1] = fmaf(wc[e], fl[e][1], a[1]);
            a[2] = fmaf(wc[e], fl[e][2], a[2]);
            a[3] = fmaf(wc[e], fl[e][3], a[3]);
        }
        f16x4 h;
        h[0] = (f16)a[0]; h[1] = (f16)a[1]; h[2] = (f16)a[2]; h[3] = (f16)a[3];
        *(f16x4*)(dst + (size_t)(tg * 32 + tt) * 65536 + e0) = h;
        if (tt < 31) {
#pragma unroll
            for (int e = 0; e < 16; ++e) wc[e] = wn[e];
        }
    }
}

// ---------------- MLP: LDS-streamed weights ----------------
__device__ __forceinline__ void stage_w128(const f16* __restrict__ src, f16* lds,
                                           int w, int lane, int rowstride) {
#pragma unroll
    for (int it = 0; it < 8; ++it) {
        int cbase = it * 256 + w * 64;
        int c = cbase + lane;
        int row = c >> 4, pc = c & 15;
        int lc = pc ^ (row & 7);
        glds16(src + (size_t)row * rowstride + lc * 8, lds + cbase * 8);
    }
}

__global__ __launch_bounds__(256) void mlp_kernel(const f16* __restrict__ Xg,
                                                  const f16* __restrict__ m1h,
                                                  const f16* __restrict__ m2h,
                                                  f16* __restrict__ Yg) {
    __shared__ f16 Hs[128 * 128];
    __shared__ f16 Ws[128 * 128];
    // XCD swizzle over 1024 blocks (= 512 tiles x 2 halves): lh pair colocates
    const int cpx = (int)gridDim.x >> 3;
    const int logical = ((int)blockIdx.x & 7) * cpx + ((int)blockIdx.x >> 3);
    const int t = logical >> 1, lh = logical & 1;
    const int n = (t >> 3) & 15;
    const int tm = (n > 0) ? (t - 8) : t;
    const int tid = threadIdx.x;
    const int lane = tid & 63, w = tid >> 6;
    const int q = lane >> 4, cl = lane & 15;
    const int l0 = w * 32;

    const f16* Xsrc = Xg + (size_t)t * 32768 + lh * 16384;
    const f16* m1b = m1h + (size_t)tm * 65536;
    const f16* m2b = m2h + (size_t)tm * 65536;

    f16x8 xf[2][4];
#pragma unroll
    for (int lt = 0; lt < 2; ++lt) {
        int l = l0 + lt * 16 + cl;
#pragma unroll
        for (int ks = 0; ks < 4; ++ks)
            xf[lt][ks] = *(const f16x8*)(Xsrc + (size_t)l * 128 + ks * 32 + q * 8);
    }
    stage_w128(m1b, Ws, w, lane, 128);
    __syncthreads();

    f32x4 acc2[2][8] = {};
#pragma unroll 1
    for (int ic = 0; ic < 4; ++ic) {
        // ---- stage1: h^T over i-chunk, Ws = m1[ic] ----
#pragma unroll
        for (int it = 0; it < 8; ++it) {
            f16x8 af[4];
#pragma unroll
            for (int ks = 0; ks < 4; ++ks) {
                int r = it * 16 + cl;
                int ch = (ks * 4 + q) ^ (r & 7);
                af[ks] = *(const f16x8*)&Ws[r * 128 + ch * 8];
            }
            f32x4 a1[2] = {};
#pragma unroll
            for (int ks = 0; ks < 4; ++ks)
#pragma unroll
                for (int lt = 0; lt < 2; ++lt)
                    a1[lt] = MFMA16(af[ks], xf[lt][ks], a1[lt]);
            int ibase = it * 16 + q * 4;
            int ch = ibase >> 3;
            int sub = (q & 1) * 8;
#pragma unroll
            for (int lt = 0; lt < 2; ++lt) {
                int l = l0 + lt * 16 + cl;
                f16x4 hv;
                hv[0] = (f16)fmaxf(a1[lt][0], 0.f);
                hv[1] = (f16)fmaxf(a1[lt][1], 0.f);
                hv[2] = (f16)fmaxf(a1[lt][2], 0.f);
                hv[3] = (f16)fmaxf(a1[lt][3], 0.f);
                *(f16x4*)((char*)Hs + (size_t)l * 256 + ((ch ^ (l & 7)) << 4) + sub) = hv;
            }
        }
        __syncthreads();
        stage_w128(m2b + ic * 128, Ws, w, lane, 512);
        __syncthreads();

        // ---- stage2: acc2 += h @ m2[ic]^T ----
        f16x8 hf[2][4];
#pragma unroll
        for (int lt = 0; lt < 2; ++lt) {
            int l = l0 + lt * 16 + cl;
#pragma unroll
            for (int ks = 0; ks < 4; ++ks) {
                int ch = (ks * 4 + q) ^ (l & 7);
                hf[lt][ks] = *(const f16x8*)&Hs[l * 128 + ch * 8];
            }
        }
#pragma unroll
        for (int nt = 0; nt < 8; ++nt) {
            f16x8 bf[4];
#pragma unroll
            for (int ks = 0; ks < 4; ++ks) {
                int r = nt * 16 + cl;
                int ch = (ks * 4 + q) ^ (r & 7);
                bf[ks] = *(const f16x8*)&Ws[r * 128 + ch * 8];
            }
#pragma unroll
            for (int lt = 0; lt < 2; ++lt)
#pragma unroll
                for (int ks = 0; ks < 4; ++ks)
                    acc2[lt][nt] = MFMA16(hf[lt][ks], bf[ks], acc2[lt][nt]);
        }
        __syncthreads();
        if (ic < 3) {
            stage_w128(m1b + (size_t)(ic + 1) * 16384, Ws, w, lane, 128);
            __syncthreads();
        }
    }
    f16* Yb = Yg + (size_t)t * 32768 + lh * 16384;
#pragma unroll
    for (int lt = 0; lt < 2; ++lt) {
#pragma unroll
        for (int nt = 0; nt < 8; ++nt) {
            int lr = l0 + lt * 16 + q * 4;
            int d = nt * 16 + cl;
#pragma unroll
            for (int r = 0; r < 4; ++r)
                Yb[(size_t)(lr + r) * 128 + d] = (f16)acc2[lt][nt][r];
        }
    }
}

extern "C" void kernel_launch(void* const* d_in, const int* in_sizes, int n_in,
                              void* d_out, int out_size, void* d_ws, size_t ws_size,
                              hipStream_t stream) {
    const float* x    = (const float*)d_in[0];
    const float* W_mh = (const float*)d_in[1];
    const float* b_mh = (const float*)d_in[2];
    const float* W_mg = (const float*)d_in[3];
    const float* b_mg = (const float*)d_in[4];
    const float* emb  = (const float*)d_in[5];
    const float* FL   = (const float*)d_in[6];
    const float* SL   = (const float*)d_in[7];

    char* ws = (char*)d_ws;
    f16*   X1h  = (f16*)(ws + 0);
    f16*   m1h  = (f16*)(ws + 33554432);
    f16*   X0h  = (f16*)(ws + 33554432);   // aliases m1h: dead after gemm1,
                                           // m1h written later by mix_kernel
    f16*   m2h  = (f16*)(ws + 100663296);
    f16*   Wmhh = (f16*)(ws + 167772160);
    f16*   Wmgh = (f16*)(ws + 169869312);
    float* part = (float*)(ws + 171966464);
    float* ew   = (float*)(ws + 173015040);

    cvt_kernel<<<512, 256, 0, stream>>>(W_mh, Wmhh, 1048576);
    cvt_kernel<<<512, 256, 0, stream>>>(W_mg, Wmgh, 1048576);
    cvt_kernel<<<8192, 256, 0, stream>>>(x, X0h, 16777216);
    gemm_bt_kernel<true><<<1024, 256, 0, stream>>>(X0h, Wmhh, b_mh, X1h,
                                                   16384, 1024, 1024);
    avg_kernel<<<256, 256, 0, stream>>>(X1h, part);
    router_kernel<<<512, 64, 0, stream>>>(part, emb, ew);
    mix_kernel<<<2048, 256, 0, stream>>>(ew, FL, SL, m1h, m2h);
    mlp_kernel<<<1024, 256, 0, stream>>>(X1h, m1h, m2h, X1h);
    gemm_bt_kernel<false><<<1024, 256, 0, stream>>>(X1h, Wmgh, b_mg, d_out,
                                                    16384, 1024, 1024);
}

// Round 9
// 228.670 us; speedup vs baseline: 1.3149x; 1.0318x over previous
//
#include <hip/hip_runtime.h>
#include <hip/hip_bf16.h>

typedef _Float16 f16;
typedef f16 f16x2 __attribute__((ext_vector_type(2)));
typedef f16 f16x4 __attribute__((ext_vector_type(4)));
typedef f16 f16x8 __attribute__((ext_vector_type(8)));
typedef float f32x2 __attribute__((ext_vector_type(2)));
typedef float f32x4 __attribute__((ext_vector_type(4)));

#define MFMA16(a, b, c) __builtin_amdgcn_mfma_f32_16x16x32_f16(a, b, c, 0, 0, 0)

__device__ __forceinline__ void glds16(const void* g, void* l) {
    __builtin_amdgcn_global_load_lds(
        (const __attribute__((address_space(1))) unsigned int*)g,
        (__attribute__((address_space(3))) unsigned int*)l, 16, 0, 0);
}

// ---------------- f32 -> f16 convert ----------------
__global__ __launch_bounds__(256) void cvt_kernel(const float* __restrict__ s,
                                                  f16* __restrict__ d, int n) {
    int i = (blockIdx.x * 256 + threadIdx.x) * 8;
    if (i >= n) return;
    float4 a = *(const float4*)(s + i);
    float4 b = *(const float4*)(s + i + 4);
    f16x8 h;
    h[0] = (f16)a.x; h[1] = (f16)a.y; h[2] = (f16)a.z; h[3] = (f16)a.w;
    h[4] = (f16)b.x; h[5] = (f16)b.y; h[6] = (f16)b.z; h[7] = (f16)b.w;
    *(f16x8*)(d + i) = h;
}

// ---------------- GEMM: C[M,N] = A[M,K] @ B[N,K]^T + bias ----------------
// 128x128 tile, BK=32, 4 waves. T2-swizzled LDS (conflict-free), XCD swizzle.
// T4 counted-vmcnt double-buffer: iter t stages buf[nxt] (4 glds/thread),
// waits vmcnt(4) = PREVIOUS iter's loads only (full iter in flight), raw
// s_barrier, compute from buf[cur], bottom s_barrier protects overwrite.
template <bool OUT_F16>
__global__ __launch_bounds__(256) void gemm_bt_kernel(
    const f16* __restrict__ A16, const f16* __restrict__ Bw,
    const float* __restrict__ bias, void* __restrict__ C_, int M, int N, int K) {
    __shared__ f16 As[2][128 * 32];
    __shared__ f16 Bs[2][128 * 32];
    const int tid = threadIdx.x;
    const int lane = tid & 63;
    const int w = tid >> 6;
    const int nblk = N >> 7;
    const int cpx = (int)gridDim.x >> 3;
    const int logical = ((int)blockIdx.x & 7) * cpx + ((int)blockIdx.x >> 3);
    const int mb = logical / nblk, nb = logical % nblk;
    const int wm = w >> 1, wn = w & 1;
    const int q = lane >> 4, cl = lane & 15;

    const f16* Bbase = Bw + (size_t)nb * 128 * K;

    // staging: row/granule per lane, swizzled source granule (loop-invariant)
    int srow[2], sg[2];
#pragma unroll
    for (int it = 0; it < 2; ++it) {
        int c = it * 256 + w * 64 + lane;
        srow[it] = c >> 2;
        sg[it] = (c & 3) ^ ((srow[it] >> 1) & 3);
    }
    const int qs = q ^ ((cl >> 1) & 3);
    const int KT = K >> 5;

    f32x4 acc[4][4] = {};

    // prologue: stage tile 0 into buffer 0
#pragma unroll
    for (int it = 0; it < 2; ++it)
        glds16(Bbase + (size_t)srow[it] * K + sg[it] * 8,
               &Bs[0][(it * 256 + w * 64) * 8]);
#pragma unroll
    for (int it = 0; it < 2; ++it)
        glds16(A16 + (size_t)(mb * 128 + srow[it]) * K + sg[it] * 8,
               &As[0][(it * 256 + w * 64) * 8]);

#pragma unroll 1
    for (int kt = 0; kt < KT; ++kt) {
        const int cur = kt & 1, nxt = cur ^ 1;
        if (kt + 1 < KT) {
            const int k1 = (kt + 1) << 5;
#pragma unroll
            for (int it = 0; it < 2; ++it)
                glds16(Bbase + (size_t)srow[it] * K + k1 + sg[it] * 8,
                       &Bs[nxt][(it * 256 + w * 64) * 8]);
#pragma unroll
            for (int it = 0; it < 2; ++it)
                glds16(A16 + (size_t)(mb * 128 + srow[it]) * K + k1 + sg[it] * 8,
                       &As[nxt][(it * 256 + w * 64) * 8]);
            asm volatile("s_waitcnt vmcnt(4)" ::: "memory");
        } else {
            asm volatile("s_waitcnt vmcnt(0)" ::: "memory");
        }
        __builtin_amdgcn_sched_barrier(0);
        __builtin_amdgcn_s_barrier();   // buf[cur] consistent across waves
        __builtin_amdgcn_sched_barrier(0);

        f16x8 af[4], bf[4];
#pragma unroll
        for (int mt = 0; mt < 4; ++mt)
            af[mt] = *(const f16x8*)&As[cur][(wm * 64 + mt * 16 + cl) * 32 + qs * 8];
#pragma unroll
        for (int nt = 0; nt < 4; ++nt)
            bf[nt] = *(const f16x8*)&Bs[cur][(wn * 64 + nt * 16 + cl) * 32 + qs * 8];
#pragma unroll
        for (int mt = 0; mt < 4; ++mt)
#pragma unroll
            for (int nt = 0; nt < 4; ++nt)
                acc[mt][nt] = MFMA16(af[mt], bf[nt], acc[mt][nt]);

        __builtin_amdgcn_sched_barrier(0);
        __builtin_amdgcn_s_barrier();   // all waves done reading buf[cur]
        __builtin_amdgcn_sched_barrier(0);
    }
    float bv[4];
#pragma unroll
    for (int nt = 0; nt < 4; ++nt) bv[nt] = bias[nb * 128 + wn * 64 + nt * 16 + cl];
#pragma unroll
    for (int mt = 0; mt < 4; ++mt) {
#pragma unroll
        for (int nt = 0; nt < 4; ++nt) {
            size_t gr = (size_t)(mb * 128 + wm * 64 + mt * 16 + q * 4);
            int gc = nb * 128 + wn * 64 + nt * 16 + cl;
#pragma unroll
            for (int r = 0; r < 4; ++r) {
                float v = acc[mt][nt][r] + bv[nt];
                if (OUT_F16)
                    ((f16*)C_)[(gr + r) * N + gc] = (f16)v;
                else
                    ((float*)C_)[(gr + r) * N + gc] = v;
            }
        }
    }
}

// ---------------- segment-average partials ----------------
__global__ __launch_bounds__(256) void avg_kernel(const f16* __restrict__ X1h,
                                                  float* __restrict__ partial) {
    const int bn = blockIdx.x >> 2, rc = blockIdx.x & 3;
    const int tid = threadIdx.x;
    const f16* base = X1h + (size_t)bn * 262144 + (size_t)rc * 65536 + tid * 4;
    float s0 = 0.f, s1 = 0.f, s2 = 0.f, s3 = 0.f;
    for (int l = 0; l < 64; ++l) {
        f16x4 v = *(const f16x4*)(base + (size_t)l * 1024);
        s0 += (float)v[0]; s1 += (float)v[1]; s2 += (float)v[2]; s3 += (float)v[3];
    }
    const float sc = 1.f / 256.f;
    float4 o = make_float4(s0 * sc, s1 * sc, s2 * sc, s3 * sc);
    *(float4*)(partial + (size_t)(bn * 4 + rc) * 1024 + tid * 4) = o;
}

// ---------------- router ----------------
__global__ __launch_bounds__(64) void router_kernel(const float* __restrict__ partial,
                                                    const float* __restrict__ emb,
                                                    float* __restrict__ ew) {
    const int t = blockIdx.x;
    const int bn = t >> 3, h = t & 7;
    const int lane = threadIdx.x;
    float acc = 0.f;
    const float* p = partial + (size_t)bn * 4096 + h * 128;
    if (lane < 16) {
        for (int d = 0; d < 128; ++d) {
            float a = p[d] + p[d + 1024] + p[d + 2048] + p[d + 3072];
            acc = fmaf(a, emb[d * 16 + lane], acc);
        }
    }
    float m = acc;
#pragma unroll
    for (int o = 8; o; o >>= 1) m = fmaxf(m, __shfl_xor(m, o));
    float pr = __expf(acc - m);
    float s = pr;
#pragma unroll
    for (int o = 8; o; o >>= 1) s += __shfl_xor(s, o);
    if (lane < 16) ew[t * 16 + lane] = pr / s;
}

// ---------------- expert mixture v3: SGPR weights, no LDS ----------------
__global__ __launch_bounds__(256) void mix_kernel(const float* __restrict__ ew,
                                                  const float* __restrict__ FL,
                                                  const float* __restrict__ SL,
                                                  f16* __restrict__ m1h,
                                                  f16* __restrict__ m2h) {
    const int bid = blockIdx.x;
    const int which = bid >> 10;
    const int tg = (bid >> 6) & 15;
    const int chunk = bid & 63;
    const float* src = which ? SL : FL;
    f16* dst = which ? m2h : m1h;
    const int tid = threadIdx.x;
    const int e0 = chunk * 1024 + tid * 4;

    f32x4 fl[16];
#pragma unroll
    for (int e = 0; e < 16; ++e)
        fl[e] = *(const f32x4*)(src + (size_t)e * 65536 + e0);

    const float* wbase = ew + (size_t)tg * 32 * 16;
    float wc[16];
#pragma unroll
    for (int e = 0; e < 16; ++e) wc[e] = wbase[e];

#pragma unroll 1
    for (int tt = 0; tt < 32; ++tt) {
        float wn[16];
        if (tt < 31) {
#pragma unroll
            for (int e = 0; e < 16; ++e) wn[e] = wbase[(tt + 1) * 16 + e];
        }
        f32x4 a = {0.f, 0.f, 0.f, 0.f};
#pragma unroll
        for (int e = 0; e < 16; ++e) {
            a[0] = fmaf(wc[e], fl[e][0], a[0]);
            a[1] = fmaf(wc[e], fl[e][1], a[1]);
            a[2] = fmaf(wc[e], fl[e][2], a[2]);
            a[3] = fmaf(wc[e], fl[e][3], a[3]);
        }
        f16x4 h;
        h[0] = (f16)a[0]; h[1] = (f16)a[1]; h[2] = (f16)a[2]; h[3] = (f16)a[3];
        *(f16x4*)(dst + (size_t)(tg * 32 + tt) * 65536 + e0) = h;
        if (tt < 31) {
#pragma unroll
            for (int e = 0; e < 16; ++e) wc[e] = wn[e];
        }
    }
}

// ---------------- MLP: LDS-streamed weights ----------------
__device__ __forceinline__ void stage_w128(const f16* __restrict__ src, f16* lds,
                                           int w, int lane, int rowstride) {
#pragma unroll
    for (int it = 0; it < 8; ++it) {
        int cbase = it * 256 + w * 64;
        int c = cbase + lane;
        int row = c >> 4, pc = c & 15;
        int lc = pc ^ (row & 7);
        glds16(src + (size_t)row * rowstride + lc * 8, lds + cbase * 8);
    }
}

__global__ __launch_bounds__(256) void mlp_kernel(const f16* __restrict__ Xg,
                                                  const f16* __restrict__ m1h,
                                                  const f16* __restrict__ m2h,
                                                  f16* __restrict__ Yg) {
    __shared__ f16 Hs[128 * 128];
    __shared__ f16 Ws[128 * 128];
    // XCD swizzle over 1024 blocks (= 512 tiles x 2 halves): lh pair colocates
    const int cpx = (int)gridDim.x >> 3;
    const int logical = ((int)blockIdx.x & 7) * cpx + ((int)blockIdx.x >> 3);
    const int t = logical >> 1, lh = logical & 1;
    const int n = (t >> 3) & 15;
    const int tm = (n > 0) ? (t - 8) : t;
    const int tid = threadIdx.x;
    const int lane = tid & 63, w = tid >> 6;
    const int q = lane >> 4, cl = lane & 15;
    const int l0 = w * 32;

    const f16* Xsrc = Xg + (size_t)t * 32768 + lh * 16384;
    const f16* m1b = m1h + (size_t)tm * 65536;
    const f16* m2b = m2h + (size_t)tm * 65536;

    f16x8 xf[2][4];
#pragma unroll
    for (int lt = 0; lt < 2; ++lt) {
        int l = l0 + lt * 16 + cl;
#pragma unroll
        for (int ks = 0; ks < 4; ++ks)
            xf[lt][ks] = *(const f16x8*)(Xsrc + (size_t)l * 128 + ks * 32 + q * 8);
    }
    stage_w128(m1b, Ws, w, lane, 128);
    __syncthreads();

    f32x4 acc2[2][8] = {};
#pragma unroll 1
    for (int ic = 0; ic < 4; ++ic) {
        // ---- stage1: h^T over i-chunk, Ws = m1[ic] ----
#pragma unroll
        for (int it = 0; it < 8; ++it) {
            f16x8 af[4];
#pragma unroll
            for (int ks = 0; ks < 4; ++ks) {
                int r = it * 16 + cl;
                int ch = (ks * 4 + q) ^ (r & 7);
                af[ks] = *(const f16x8*)&Ws[r * 128 + ch * 8];
            }
            f32x4 a1[2] = {};
#pragma unroll
            for (int ks = 0; ks < 4; ++ks)
#pragma unroll
                for (int lt = 0; lt < 2; ++lt)
                    a1[lt] = MFMA16(af[ks], xf[lt][ks], a1[lt]);
            int ibase = it * 16 + q * 4;
            int ch = ibase >> 3;
            int sub = (q & 1) * 8;
#pragma unroll
            for (int lt = 0; lt < 2; ++lt) {
                int l = l0 + lt * 16 + cl;
                f16x4 hv;
                hv[0] = (f16)fmaxf(a1[lt][0], 0.f);
                hv[1] = (f16)fmaxf(a1[lt][1], 0.f);
                hv[2] = (f16)fmaxf(a1[lt][2], 0.f);
                hv[3] = (f16)fmaxf(a1[lt][3], 0.f);
                *(f16x4*)((char*)Hs + (size_t)l * 256 + ((ch ^ (l & 7)) << 4) + sub) = hv;
            }
        }
        __syncthreads();
        stage_w128(m2b + ic * 128, Ws, w, lane, 512);
        __syncthreads();

        // ---- stage2: acc2 += h @ m2[ic]^T ----
        f16x8 hf[2][4];
#pragma unroll
        for (int lt = 0; lt < 2; ++lt) {
            int l = l0 + lt * 16 + cl;
#pragma unroll
            for (int ks = 0; ks < 4; ++ks) {
                int ch = (ks * 4 + q) ^ (l & 7);
                hf[lt][ks] = *(const f16x8*)&Hs[l * 128 + ch * 8];
            }
        }
#pragma unroll
        for (int nt = 0; nt < 8; ++nt) {
            f16x8 bf[4];
#pragma unroll
            for (int ks = 0; ks < 4; ++ks) {
                int r = nt * 16 + cl;
                int ch = (ks * 4 + q) ^ (r & 7);
                bf[ks] = *(const f16x8*)&Ws[r * 128 + ch * 8];
            }
#pragma unroll
            for (int lt = 0; lt < 2; ++lt)
#pragma unroll
                for (int ks = 0; ks < 4; ++ks)
                    acc2[lt][nt] = MFMA16(hf[lt][ks], bf[ks], acc2[lt][nt]);
        }
        __syncthreads();
        if (ic < 3) {
            stage_w128(m1b + (size_t)(ic + 1) * 16384, Ws, w, lane, 128);
            __syncthreads();
        }
    }
    f16* Yb = Yg + (size_t)t * 32768 + lh * 16384;
#pragma unroll
    for (int lt = 0; lt < 2; ++lt) {
#pragma unroll
        for (int nt = 0; nt < 8; ++nt) {
            int lr = l0 + lt * 16 + q * 4;
            int d = nt * 16 + cl;
#pragma unroll
            for (int r = 0; r < 4; ++r)
                Yb[(size_t)(lr + r) * 128 + d] = (f16)acc2[lt][nt][r];
        }
    }
}

extern "C" void kernel_launch(void* const* d_in, const int* in_sizes, int n_in,
                              void* d_out, int out_size, void* d_ws, size_t ws_size,
                              hipStream_t stream) {
    const float* x    = (const float*)d_in[0];
    const float* W_mh = (const float*)d_in[1];
    const float* b_mh = (const float*)d_in[2];
    const float* W_mg = (const float*)d_in[3];
    const float* b_mg = (const float*)d_in[4];
    const float* emb  = (const float*)d_in[5];
    const float* FL   = (const float*)d_in[6];
    const float* SL   = (const float*)d_in[7];

    char* ws = (char*)d_ws;
    f16*   X1h  = (f16*)(ws + 0);
    f16*   m1h  = (f16*)(ws + 33554432);
    f16*   X0h  = (f16*)(ws + 33554432);   // aliases m1h: dead after gemm1,
                                           // m1h written later by mix_kernel
    f16*   m2h  = (f16*)(ws + 100663296);
    f16*   Wmhh = (f16*)(ws + 167772160);
    f16*   Wmgh = (f16*)(ws + 169869312);
    float* part = (float*)(ws + 171966464);
    float* ew   = (float*)(ws + 173015040);

    cvt_kernel<<<512, 256, 0, stream>>>(W_mh, Wmhh, 1048576);
    cvt_kernel<<<512, 256, 0, stream>>>(W_mg, Wmgh, 1048576);
    cvt_kernel<<<8192, 256, 0, stream>>>(x, X0h, 16777216);
    gemm_bt_kernel<true><<<1024, 256, 0, stream>>>(X0h, Wmhh, b_mh, X1h,
                                                   16384, 1024, 1024);
    avg_kernel<<<256, 256, 0, stream>>>(X1h, part);
    router_kernel<<<512, 64, 0, stream>>>(part, emb, ew);
    mix_kernel<<<2048, 256, 0, stream>>>(ew, FL, SL, m1h, m2h);
    mlp_kernel<<<1024, 256, 0, stream>>>(X1h, m1h, m2h, X1h);
    gemm_bt_kernel<false><<<1024, 256, 0, stream>>>(X1h, Wmgh, b_mg, d_out,
                                                    16384, 1024, 1024);
}

// Round 11
// 209.457 us; speedup vs baseline: 1.4356x; 1.0917x over previous
//
#include <hip/hip_runtime.h>
#include <hip/hip_bf16.h>

typedef _Float16 f16;
typedef f16 f16x2 __attribute__((ext_vector_type(2)));
typedef f16 f16x4 __attribute__((ext_vector_type(4)));
typedef f16 f16x8 __attribute__((ext_vector_type(8)));
typedef float f32x2 __attribute__((ext_vector_type(2)));
typedef float f32x4 __attribute__((ext_vector_type(4)));

#define MFMA16(a, b, c) __builtin_amdgcn_mfma_f32_16x16x32_f16(a, b, c, 0, 0, 0)

__device__ __forceinline__ void glds16(const void* g, void* l) {
    __builtin_amdgcn_global_load_lds(
        (const __attribute__((address_space(1))) unsigned int*)g,
        (__attribute__((address_space(3))) unsigned int*)l, 16, 0, 0);
}

// ---------------- f32 -> f16 convert ----------------
__global__ __launch_bounds__(256) void cvt_kernel(const float* __restrict__ s,
                                                  f16* __restrict__ d, int n) {
    int i = (blockIdx.x * 256 + threadIdx.x) * 8;
    if (i >= n) return;
    float4 a = *(const float4*)(s + i);
    float4 b = *(const float4*)(s + i + 4);
    f16x8 h;
    h[0] = (f16)a.x; h[1] = (f16)a.y; h[2] = (f16)a.z; h[3] = (f16)a.w;
    h[4] = (f16)b.x; h[5] = (f16)b.y; h[6] = (f16)b.z; h[7] = (f16)b.w;
    *(f16x8*)(d + i) = h;
}

// ============ GEMM 256x256 8-phase (T2+T3+T4+T5) ============
// 512 thr / 8 waves. Quadrant decomposition: per phase all waves read A-half
// MH / B-half NH and compute C quadrant (MH,NH); within a quadrant wave
// (wm,wn) owns rows wm*64+[0,64) x cols wn*32+[0,32).
//   acc[MH*4+mt][NH*2+nt]; A row = wm*64+mt*16+cl; B row = wn*32+nt*16+cl.
// BK=64; LDS = 2 dbuf x {A,B} x 2 half x 128x64 f16 = 128KB.
// Granule XOR swizzle g^=(row&7) both sides (stage source + read).
// Fences (per-wave counted vmcnt before closing barrier):
//   VM8@p1,p2,p4,p8; VM6@p5; prologue VM8; epilogue VM4@p4, VM0@p5.

template <int MH, int NH, bool LOADA>
__device__ __forceinline__ void phase_rw(const f16* Aslab, const f16* Bslab,
                                         f16x8 (&af)[4][2], f16x8 (&bf)[2][2],
                                         int cl, int q, int wm, int wn) {
    if (LOADA) {
#pragma unroll
        for (int mt = 0; mt < 4; ++mt)
#pragma unroll
            for (int ks = 0; ks < 2; ++ks)
                af[mt][ks] =
                    *(const f16x8*)&Aslab[(wm * 64 + mt * 16 + cl) * 64 +
                                          ((ks * 4 + q) ^ (cl & 7)) * 8];
    }
#pragma unroll
    for (int nt = 0; nt < 2; ++nt)
#pragma unroll
        for (int ks = 0; ks < 2; ++ks)
            bf[nt][ks] = *(const f16x8*)&Bslab[(wn * 32 + nt * 16 + cl) * 64 +
                                               ((ks * 4 + q) ^ (cl & 7)) * 8];
}

template <int MH, int NH>
__device__ __forceinline__ void phase_mm(f16x8 (&af)[4][2], f16x8 (&bf)[2][2],
                                         f32x4 (&acc)[8][4]) {
    __builtin_amdgcn_s_setprio(1);
#pragma unroll
    for (int mt = 0; mt < 4; ++mt)
#pragma unroll
        for (int nt = 0; nt < 2; ++nt)
#pragma unroll
            for (int ks = 0; ks < 2; ++ks)
                acc[MH * 4 + mt][NH * 2 + nt] =
                    MFMA16(af[mt][ks], bf[nt][ks], acc[MH * 4 + mt][NH * 2 + nt]);
    __builtin_amdgcn_s_setprio(0);
}

__device__ __forceinline__ void stage_half(const f16* gsrc, int ldk, f16* ldst,
                                           int w, int lane) {
#pragma unroll
    for (int j = 0; j < 2; ++j) {
        int idx = j * 512 + w * 64 + lane;
        int rr = idx >> 3;
        int gs = (idx & 7) ^ (rr & 7);
        glds16(gsrc + (size_t)rr * ldk + gs * 8, ldst + (j * 512 + w * 64) * 8);
    }
}

#define VM8 asm volatile("s_waitcnt vmcnt(8)" ::: "memory")
#define VM6 asm volatile("s_waitcnt vmcnt(6)" ::: "memory")
#define VM4 asm volatile("s_waitcnt vmcnt(4)" ::: "memory")
#define VM0 asm volatile("s_waitcnt vmcnt(0)" ::: "memory")
#define VMN do {} while (0)
#define SB0 __builtin_amdgcn_sched_barrier(0)

#define SA(DB, H, KT) stage_half(A16 + (size_t)(mb * 256 + (H)*128) * K + (KT)*64, \
                                 K, Ad[DB][H], w, lane)
#define SBm(DB, H, KT) stage_half(Bw + (size_t)(nb * 256 + (H)*128) * K + (KT)*64, \
                                  K, Bd[DB][H], w, lane)

#define PH(DB, MH, NH, LA, STAGE, VMC)                                    \
    phase_rw<MH, NH, LA>(Ad[DB][MH], Bd[DB][NH], af, bf, cl, q, wm, wn);  \
    STAGE;                                                                \
    SB0; __builtin_amdgcn_s_barrier(); SB0;                               \
    phase_mm<MH, NH>(af, bf, acc);                                        \
    VMC;                                                                  \
    SB0; __builtin_amdgcn_s_barrier(); SB0;

template <bool OUT_F16>
__global__ __launch_bounds__(512, 2) void gemm256_kernel(
    const f16* __restrict__ A16, const f16* __restrict__ Bw,
    const float* __restrict__ bias, void* __restrict__ C_, int M, int N, int K) {
    __shared__ f16 Ad[2][2][128 * 64];
    __shared__ f16 Bd[2][2][128 * 64];
    const int tid = threadIdx.x;
    const int lane = tid & 63;
    const int w = tid >> 6;
    const int wm = w >> 2, wn = w & 3;
    const int q = lane >> 4, cl = lane & 15;
    const int nblk = N >> 8;
    const int cpx = (int)gridDim.x >> 3;
    const int logical = ((int)blockIdx.x & 7) * cpx + ((int)blockIdx.x >> 3);
    const int mb = logical / nblk, nb = logical % nblk;

    f32x4 acc[8][4] = {};
    f16x8 af[4][2], bf[2][2];
    const int ITERS = (K >> 6) / 2;  // 2 K-tiles per iter

    // prologue: d0 full (K-tile 0) + d1 half0s (K-tile 1) = 12 loads, in order
    SA(0, 0, 0); SBm(0, 0, 0); SBm(0, 1, 0); SA(0, 1, 0);
    SA(1, 0, 1); SBm(1, 0, 1);
    VM8;
    SB0; __builtin_amdgcn_s_barrier(); SB0;

#pragma unroll 1
    for (int i = 0; i < ITERS - 1; ++i) {
        const int k2 = 2 * i;
        PH(0, 0, 0, true,  SA(1, 1, k2 + 1),  VM8)   // p1
        PH(0, 0, 1, false, SBm(1, 1, k2 + 1), VM8)   // p2
        PH(0, 1, 0, true,  SA(0, 0, k2 + 2),  VMN)   // p3
        PH(0, 1, 1, false, SBm(0, 0, k2 + 2), VM8)   // p4
        PH(1, 0, 0, true,  SBm(0, 1, k2 + 2), VM6)   // p5
        PH(1, 0, 1, false, SA(0, 1, k2 + 2),  VMN)   // p6
        PH(1, 1, 0, true,  SA(1, 0, k2 + 3),  VMN)   // p7
        PH(1, 1, 1, false, SBm(1, 0, k2 + 3), VM8)   // p8
    }
    {   // epilogue iter: K-tiles 2*ITERS-2 (d0), 2*ITERS-1 (d1)
        const int kl = 2 * ITERS - 1;
        PH(0, 0, 0, true,  SA(1, 1, kl),  VM8)
        PH(0, 0, 1, false, SBm(1, 1, kl), VM8)
        PH(0, 1, 0, true,  VMN,           VMN)
        PH(0, 1, 1, false, VMN,           VM4)
        PH(1, 0, 0, true,  VMN,           VM0)
        PH(1, 0, 1, false, VMN,           VMN)
        PH(1, 1, 0, true,  VMN,           VMN)
        PH(1, 1, 1, false, VMN,           VMN)
    }

    // C epilogue: row = quadrant(mt7>>2)*128 + wm*64 + (mt7&3)*16 + q*4
    //             col = quadrant(nt4>>1)*128 + wn*32 + (nt4&1)*16 + cl
#pragma unroll
    for (int mt7 = 0; mt7 < 8; ++mt7) {
#pragma unroll
        for (int nt4 = 0; nt4 < 4; ++nt4) {
            int row0 = mb * 256 + (mt7 >> 2) * 128 + wm * 64 + (mt7 & 3) * 16 + q * 4;
            int col = nb * 256 + (nt4 >> 1) * 128 + wn * 32 + (nt4 & 1) * 16 + cl;
            float bv = bias[col];
#pragma unroll
            for (int r = 0; r < 4; ++r) {
                float v = acc[mt7][nt4][r] + bv;
                if (OUT_F16)
                    ((f16*)C_)[(size_t)(row0 + r) * N + col] = (f16)v;
                else
                    ((float*)C_)[(size_t)(row0 + r) * N + col] = v;
            }
        }
    }
}

// ---------------- segment-average partials ----------------
__global__ __launch_bounds__(256) void avg_kernel(const f16* __restrict__ X1h,
                                                  float* __restrict__ partial) {
    const int bn = blockIdx.x >> 2, rc = blockIdx.x & 3;
    const int tid = threadIdx.x;
    const f16* base = X1h + (size_t)bn * 262144 + (size_t)rc * 65536 + tid * 4;
    float s0 = 0.f, s1 = 0.f, s2 = 0.f, s3 = 0.f;
    for (int l = 0; l < 64; ++l) {
        f16x4 v = *(const f16x4*)(base + (size_t)l * 1024);
        s0 += (float)v[0]; s1 += (float)v[1]; s2 += (float)v[2]; s3 += (float)v[3];
    }
    const float sc = 1.f / 256.f;
    float4 o = make_float4(s0 * sc, s1 * sc, s2 * sc, s3 * sc);
    *(float4*)(partial + (size_t)(bn * 4 + rc) * 1024 + tid * 4) = o;
}

// ---------------- router ----------------
__global__ __launch_bounds__(64) void router_kernel(const float* __restrict__ partial,
                                                    const float* __restrict__ emb,
                                                    float* __restrict__ ew) {
    const int t = blockIdx.x;
    const int bn = t >> 3, h = t & 7;
    const int lane = threadIdx.x;
    float acc = 0.f;
    const float* p = partial + (size_t)bn * 4096 + h * 128;
    if (lane < 16) {
        for (int d = 0; d < 128; ++d) {
            float a = p[d] + p[d + 1024] + p[d + 2048] + p[d + 3072];
            acc = fmaf(a, emb[d * 16 + lane], acc);
        }
    }
    float m = acc;
#pragma unroll
    for (int o = 8; o; o >>= 1) m = fmaxf(m, __shfl_xor(m, o));
    float pr = __expf(acc - m);
    float s = pr;
#pragma unroll
    for (int o = 8; o; o >>= 1) s += __shfl_xor(s, o);
    if (lane < 16) ew[t * 16 + lane] = pr / s;
}

// ---------------- expert mixture v3: SGPR weights, no LDS ----------------
__global__ __launch_bounds__(256) void mix_kernel(const float* __restrict__ ew,
                                                  const float* __restrict__ FL,
                                                  const float* __restrict__ SL,
                                                  f16* __restrict__ m1h,
                                                  f16* __restrict__ m2h) {
    const int bid = blockIdx.x;
    const int which = bid >> 10;
    const int tg = (bid >> 6) & 15;
    const int chunk = bid & 63;
    const float* src = which ? SL : FL;
    f16* dst = which ? m2h : m1h;
    const int tid = threadIdx.x;
    const int e0 = chunk * 1024 + tid * 4;

    f32x4 fl[16];
#pragma unroll
    for (int e = 0; e < 16; ++e)
        fl[e] = *(const f32x4*)(src + (size_t)e * 65536 + e0);

    const float* wbase = ew + (size_t)tg * 32 * 16;
    float wc[16];
#pragma unroll
    for (int e = 0; e < 16; ++e) wc[e] = wbase[e];

#pragma unroll 1
    for (int tt = 0; tt < 32; ++tt) {
        float wn2[16];
        if (tt < 31) {
#pragma unroll
            for (int e = 0; e < 16; ++e) wn2[e] = wbase[(tt + 1) * 16 + e];
        }
        f32x4 a = {0.f, 0.f, 0.f, 0.f};
#pragma unroll
        for (int e = 0; e < 16; ++e) {
            a[0] = fmaf(wc[e], fl[e][0], a[0]);
            a[1] = fmaf(wc[e], fl[e][1], a[1]);
            a[2] = fmaf(wc[e], fl[e][2], a[2]);
            a[3] = fmaf(wc[e], fl[e][3], a[3]);
        }
        f16x4 h;
        h[0] = (f16)a[0]; h[1] = (f16)a[1]; h[2] = (f16)a[2]; h[3] = (f16)a[3];
        *(f16x4*)(dst + (size_t)(tg * 32 + tt) * 65536 + e0) = h;
        if (tt < 31) {
#pragma unroll
            for (int e = 0; e < 16; ++e) wc[e] = wn2[e];
        }
    }
}

// ---------------- MLP: LDS-streamed weights ----------------
__device__ __forceinline__ void stage_w128(const f16* __restrict__ src, f16* lds,
                                           int w, int lane, int rowstride) {
#pragma unroll
    for (int it = 0; it < 8; ++it) {
        int cbase = it * 256 + w * 64;
        int c = cbase + lane;
        int row = c >> 4, pc = c & 15;
        int lc = pc ^ (row & 7);
        glds16(src + (size_t)row * rowstride + lc * 8, lds + cbase * 8);
    }
}

__global__ __launch_bounds__(256) void mlp_kernel(const f16* __restrict__ Xg,
                                                  const f16* __restrict__ m1h,
                                                  const f16* __restrict__ m2h,
                                                  f16* __restrict__ Yg) {
    __shared__ f16 Hs[128 * 128];
    __shared__ f16 Ws[128 * 128];
    const int cpx = (int)gridDim.x >> 3;
    const int logical = ((int)blockIdx.x & 7) * cpx + ((int)blockIdx.x >> 3);
    const int t = logical >> 1, lh = logical & 1;
    const int n = (t >> 3) & 15;
    const int tm = (n > 0) ? (t - 8) : t;
    const int tid = threadIdx.x;
    const int lane = tid & 63, w = tid >> 6;
    const int q = lane >> 4, cl = lane & 15;
    const int l0 = w * 32;

    const f16* Xsrc = Xg + (size_t)t * 32768 + lh * 16384;
    const f16* m1b = m1h + (size_t)tm * 65536;
    const f16* m2b = m2h + (size_t)tm * 65536;

    f16x8 xf[2][4];
#pragma unroll
    for (int lt = 0; lt < 2; ++lt) {
        int l = l0 + lt * 16 + cl;
#pragma unroll
        for (int ks = 0; ks < 4; ++ks)
            xf[lt][ks] = *(const f16x8*)(Xsrc + (size_t)l * 128 + ks * 32 + q * 8);
    }
    stage_w128(m1b, Ws, w, lane, 128);
    __syncthreads();

    f32x4 acc2[2][8] = {};
#pragma unroll 1
    for (int ic = 0; ic < 4; ++ic) {
#pragma unroll
        for (int it = 0; it < 8; ++it) {
            f16x8 af2[4];
#pragma unroll
            for (int ks = 0; ks < 4; ++ks) {
                int r = it * 16 + cl;
                int ch = (ks * 4 + q) ^ (r & 7);
                af2[ks] = *(const f16x8*)&Ws[r * 128 + ch * 8];
            }
            f32x4 a1[2] = {};
#pragma unroll
            for (int ks = 0; ks < 4; ++ks)
#pragma unroll
                for (int lt = 0; lt < 2; ++lt)
                    a1[lt] = MFMA16(af2[ks], xf[lt][ks], a1[lt]);
            int ibase = it * 16 + q * 4;
            int ch = ibase >> 3;
            int sub = (q & 1) * 8;
#pragma unroll
            for (int lt = 0; lt < 2; ++lt) {
                int l = l0 + lt * 16 + cl;
                f16x4 hv;
                hv[0] = (f16)fmaxf(a1[lt][0], 0.f);
                hv[1] = (f16)fmaxf(a1[lt][1], 0.f);
                hv[2] = (f16)fmaxf(a1[lt][2], 0.f);
                hv[3] = (f16)fmaxf(a1[lt][3], 0.f);
                *(f16x4*)((char*)Hs + (size_t)l * 256 + ((ch ^ (l & 7)) << 4) + sub) = hv;
            }
        }
        __syncthreads();
        stage_w128(m2b + ic * 128, Ws, w, lane, 512);
        __syncthreads();

        f16x8 hf[2][4];
#pragma unroll
        for (int lt = 0; lt < 2; ++lt) {
            int l = l0 + lt * 16 + cl;
#pragma unroll
            for (int ks = 0; ks < 4; ++ks) {
                int ch = (ks * 4 + q) ^ (l & 7);
                hf[lt][ks] = *(const f16x8*)&Hs[l * 128 + ch * 8];
            }
        }
#pragma unroll
        for (int nt = 0; nt < 8; ++nt) {
            f16x8 bf2[4];
#pragma unroll
            for (int ks = 0; ks < 4; ++ks) {
                int r = nt * 16 + cl;
                int ch = (ks * 4 + q) ^ (r & 7);
                bf2[ks] = *(const f16x8*)&Ws[r * 128 + ch * 8];
            }
#pragma unroll
            for (int lt = 0; lt < 2; ++lt)
#pragma unroll
                for (int ks = 0; ks < 4; ++ks)
                    acc2[lt][nt] = MFMA16(hf[lt][ks], bf2[ks], acc2[lt][nt]);
        }
        __syncthreads();
        if (ic < 3) {
            stage_w128(m1b + (size_t)(ic + 1) * 16384, Ws, w, lane, 128);
            __syncthreads();
        }
    }
    f16* Yb = Yg + (size_t)t * 32768 + lh * 16384;
#pragma unroll
    for (int lt = 0; lt < 2; ++lt) {
#pragma unroll
        for (int nt = 0; nt < 8; ++nt) {
            int lr = l0 + lt * 16 + q * 4;
            int d = nt * 16 + cl;
#pragma unroll
            for (int r = 0; r < 4; ++r)
                Yb[(size_t)(lr + r) * 128 + d] = (f16)acc2[lt][nt][r];
        }
    }
}

extern "C" void kernel_launch(void* const* d_in, const int* in_sizes, int n_in,
                              void* d_out, int out_size, void* d_ws, size_t ws_size,
                              hipStream_t stream) {
    const float* x    = (const float*)d_in[0];
    const float* W_mh = (const float*)d_in[1];
    const float* b_mh = (const float*)d_in[2];
    const float* W_mg = (const float*)d_in[3];
    const float* b_mg = (const float*)d_in[4];
    const float* emb  = (const float*)d_in[5];
    const float* FL   = (const float*)d_in[6];
    const float* SL   = (const float*)d_in[7];

    char* ws = (char*)d_ws;
    f16*   X1h  = (f16*)(ws + 0);
    f16*   m1h  = (f16*)(ws + 33554432);
    f16*   X0h  = (f16*)(ws + 33554432);   // aliases m1h (dead interval)
    f16*   m2h  = (f16*)(ws + 100663296);
    f16*   Wmhh = (f16*)(ws + 167772160);
    f16*   Wmgh = (f16*)(ws + 169869312);
    float* part = (float*)(ws + 171966464);
    float* ew   = (float*)(ws + 173015040);

    cvt_kernel<<<512, 256, 0, stream>>>(W_mh, Wmhh, 1048576);
    cvt_kernel<<<512, 256, 0, stream>>>(W_mg, Wmgh, 1048576);
    cvt_kernel<<<8192, 256, 0, stream>>>(x, X0h, 16777216);
    gemm256_kernel<true><<<256, 512, 0, stream>>>(X0h, Wmhh, b_mh, X1h,
                                                  16384, 1024, 1024);
    avg_kernel<<<256, 256, 0, stream>>>(X1h, part);
    router_kernel<<<512, 64, 0, stream>>>(part, emb, ew);
    mix_kernel<<<2048, 256, 0, stream>>>(ew, FL, SL, m1h, m2h);
    mlp_kernel<<<1024, 256, 0, stream>>>(X1h, m1h, m2h, X1h);
    gemm256_kernel<false><<<256, 512, 0, stream>>>(X1h, Wmgh, b_mg, d_out,
                                                   16384, 1024, 1024);
}